// Round 10
// baseline (253.285 us; speedup 1.0000x reference)
//
#include <hip/hip_runtime.h>
#include <stdint.h>

typedef unsigned short u16;
typedef __attribute__((ext_vector_type(8))) short short8;
typedef __attribute__((ext_vector_type(4))) float f32x4;
typedef __attribute__((ext_vector_type(4))) unsigned short ushort4_t;
typedef __attribute__((ext_vector_type(4))) float float4_t;

#define DEV_INLINE __device__ __forceinline__

DEV_INLINE u16 f2bf(float f) {
    union { float f; unsigned u; } x; x.f = f;
    unsigned u = x.u;
    unsigned r = (u + 0x7FFFu + ((u >> 16) & 1u)) >> 16;
    return (u16)r;
}

DEV_INLINE float bf2f(u16 b) {
    union { unsigned u; float f; } x; x.u = ((unsigned)b) << 16;
    return x.f;
}

DEV_INLINE float fexp2(float x) {
    float r;
    asm("v_exp_f32 %0, %1" : "=v"(r) : "v"(x));
    return r;
}

DEV_INLINE unsigned cvtpk_bf16(float lo, float hi) {
    unsigned r;
    asm("v_cvt_pk_bf16_f32 %0, %1, %2" : "=v"(r) : "v"(lo), "v"(hi));
    return r;
}

template <int CTRL>
DEV_INLINE float dppmax(float x) {
    union { float f; int i; } u; u.f = x;
    int y = __builtin_amdgcn_update_dpp(u.i, u.i, CTRL, 0xf, 0xf, true);
    union { int i; float f; } v; v.i = y;
    return fmaxf(x, v.f);
}

// max across each 16-lane group, no LDS
DEV_INLINE float rmax16(float x) {
    x = dppmax<0xB1>(x);    // quad_perm xor 1
    x = dppmax<0x4E>(x);    // quad_perm xor 2
    x = dppmax<0x141>(x);   // row_half_mirror (xor 7)
    x = dppmax<0x140>(x);   // row_mirror (xor 15)
    return x;
}

// ---------------- fused convert (5 plain f32->bf16 segments) ----------------
__global__ void conv_multi(const float* __restrict__ s0, u16* __restrict__ d0, long e0,
                           const float* __restrict__ s1, u16* __restrict__ d1, long e1,
                           const float* __restrict__ s2, u16* __restrict__ d2, long e2,
                           const float* __restrict__ s3, u16* __restrict__ d3, long e3,
                           const float* __restrict__ s4, u16* __restrict__ d4, long e4) {
    long i = (long)blockIdx.x * 256 + threadIdx.x;
    const float* s; u16* d; long base;
    if      (i < e0) { s = s0; d = d0; base = 0; }
    else if (i < e1) { s = s1; d = d1; base = e0; }
    else if (i < e2) { s = s2; d = d2; base = e1; }
    else if (i < e3) { s = s3; d = d3; base = e2; }
    else if (i < e4) { s = s4; d = d4; base = e3; }
    else return;
    long j = i - base;
    float4_t v = ((const float4_t*)s)[j];
    ushort4_t o;
    o.x = f2bf(v.x); o.y = f2bf(v.y); o.z = f2bf(v.z); o.w = f2bf(v.w);
    ((ushort4_t*)d)[j] = o;
}

__global__ void conv_pad(const float* __restrict__ in, u16* __restrict__ out,
                         int rows_valid, long n4, int cols4) {
    long i = (long)blockIdx.x * blockDim.x + threadIdx.x;
    if (i >= n4) return;
    long row = i / cols4;
    ushort4_t o; o.x = 0; o.y = 0; o.z = 0; o.w = 0;
    if (row < rows_valid) {
        float4_t v = ((const float4_t*)in)[i];
        o.x = f2bf(v.x); o.y = f2bf(v.y); o.z = f2bf(v.z); o.w = f2bf(v.w);
    }
    ((ushort4_t*)out)[i] = o;
}

// ---------------- GEMM 64x128, 3-deep pipelined (T3+T4 counted vmcnt) ----------------
#define BK 32

DEV_INLINE void gload16(const u16* g, u16* l) {
    __builtin_amdgcn_global_load_lds((const __attribute__((address_space(1))) unsigned int*)g,
                                     (__attribute__((address_space(3))) unsigned int*)l,
                                     16, 0, 0);
}

template <typename OT>
__global__ __launch_bounds__(256) void gemm64_p3(const u16* __restrict__ A, const u16* __restrict__ B,
                                                 OT* __restrict__ C, int M, int N, int K) {
    __shared__ u16 As[3][64 * BK];
    __shared__ u16 Bs[3][128 * BK];
    const int tid = threadIdx.x;
    const int wid = tid >> 6, lane = tid & 63;
    const int lm = lane & 15, lk = lane >> 4;
    const long bm = (long)blockIdx.y * 64, bn = (long)blockIdx.x * 128;

    f32x4 acc[4][2] = {};

    const int rowS = lane >> 2;
    const int colS = ((lane & 3) ^ ((lane >> 3) & 3)) * 8;  // pre-swizzled source col
    const int cs = (lm >> 1) & 3;                           // frag-read XOR
    const u16* Ag = A + (bm + wid * 16 + rowS) * (long)K + colS;
    const u16* Bg = B + (bn + wid * 32 + rowS) * (long)K + colS;
    const int aoff = wid * 16 * BK;
    const int boff = wid * 32 * BK;

    const int nst = K / BK;

#define STAGE(kk, bb)                                                             \
    do {                                                                          \
        gload16(Ag + (kk) * BK, &As[bb][aoff]);                                   \
        gload16(Bg + (kk) * BK, &Bs[bb][boff]);                                   \
        gload16(Bg + 16 * (long)K + (kk) * BK, &Bs[bb][boff + 16 * BK]);          \
    } while (0)

    // prologue: 2 tiles in flight
    STAGE(0, 0);
    STAGE(1, 1);
    asm volatile("s_waitcnt vmcnt(3)" ::: "memory");   // tile 0 landed; tile 1 in flight
    __builtin_amdgcn_s_barrier();
    asm volatile("" ::: "memory");

    for (int k = 0; k < nst; ++k) {
        const int cur = k % 3;
        const bool more = (k + 2 < nst);
        if (more) {
            const int nb = (k + 2) % 3;
            STAGE(k + 2, nb);
        }
        short8 af[4], bfr[2];
#pragma unroll
        for (int m = 0; m < 4; ++m)
            af[m] = *(const short8*)&As[cur][(m * 16 + lm) * BK + (lk ^ cs) * 8];
#pragma unroll
        for (int n = 0; n < 2; ++n)
            bfr[n] = *(const short8*)&Bs[cur][(wid * 32 + n * 16 + lm) * BK + (lk ^ cs) * 8];
#pragma unroll
        for (int m = 0; m < 4; ++m)
#pragma unroll
            for (int n = 0; n < 2; ++n)
                acc[m][n] = __builtin_amdgcn_mfma_f32_16x16x32_bf16(af[m], bfr[n], acc[m][n], 0, 0, 0);
        // wait tile k+1 (3 oldest of my outstanding loads); tile k+2's 3 stay in flight
        if (more) asm volatile("s_waitcnt vmcnt(3)" ::: "memory");
        else      asm volatile("s_waitcnt vmcnt(0)" ::: "memory");
        __builtin_amdgcn_s_barrier();
        asm volatile("" ::: "memory");
    }
#undef STAGE

#pragma unroll
    for (int m = 0; m < 4; ++m)
#pragma unroll
        for (int n = 0; n < 2; ++n)
#pragma unroll
            for (int r = 0; r < 4; ++r) {
                long idx = (bm + m * 16 + lk * 4 + r) * (long)N + bn + wid * 32 + n * 16 + lm;
                if constexpr (sizeof(OT) == 4) C[idx] = acc[m][n][r];
                else                           C[idx] = f2bf(acc[m][n][r]);
            }
}

// ---------------- RMSNorm (f32 in, bf16 out) ----------------
__global__ __launch_bounds__(256) void rmsnorm_bf16(const float* __restrict__ in, const float* __restrict__ w,
                                                    u16* __restrict__ out, int ldin, int ldout, int ncols) {
    const int row = blockIdx.x, tid = threadIdx.x;
    const float* x = in + (long)row * ldin;
    float ss = 0.f;
    for (int c = tid; c < ncols; c += 256) { float v = x[c]; ss = fmaf(v, v, ss); }
#pragma unroll
    for (int off = 32; off > 0; off >>= 1) ss += __shfl_down(ss, off);
    __shared__ float part[4];
    if ((tid & 63) == 0) part[tid >> 6] = ss;
    __syncthreads();
    float tot = part[0] + part[1] + part[2] + part[3];
    float rs = rsqrtf(tot / (float)ncols + 1e-6f);
    for (int c = tid; c < ncols; c += 256) out[(long)row * ldout + c] = f2bf(x[c] * rs * w[c]);
}

// ---------------- k_pe RoPE -> K[:, :, 128:192] for all heads ----------------
__global__ void rope_k(const float* __restrict__ ckv, const int* __restrict__ pos,
                       const float* __restrict__ cosT, const float* __restrict__ sinT,
                       u16* __restrict__ Kb) {
    int idx = blockIdx.x * 256 + threadIdx.x;
    if (idx >= 2048 * 32) return;
    int s = idx >> 5, j = idx & 31;
    long p = pos[s];
    const float* row = ckv + (long)s * 2176 + 2048;
    float x0 = row[2 * j], x1 = row[2 * j + 1];
    float c0 = cosT[p * 64 + j],      s0 = sinT[p * 64 + j];
    float c1 = cosT[p * 64 + 32 + j], s1 = sinT[p * 64 + 32 + j];
    u16 o0 = f2bf(x0 * c0 - x1 * s0);
    u16 o1 = f2bf(x1 * c1 + x0 * s1);
#pragma unroll
    for (int h = 0; h < 16; ++h) {
        u16* kr = Kb + ((long)h * 2048 + s) * 192 + 128;
        kr[j] = o0; kr[32 + j] = o1;
    }
}

// ---------------- assemble Q (bf16 in, RoPE on last 64 dims) ----------------
__global__ void build_q(const u16* __restrict__ q, const int* __restrict__ pos,
                        const float* __restrict__ cosT, const float* __restrict__ sinT,
                        u16* __restrict__ Qb) {
    long idx = (long)blockIdx.x * 256 + threadIdx.x;
    if (idx >= 16L * 2048 * 192) return;
    int d = (int)(idx % 192);
    int s = (int)((idx / 192) % 2048);
    int h = (int)(idx / (192L * 2048));
    const u16* qrow = q + (long)s * 3072 + h * 192;
    u16 outv;
    if (d < 128) {
        outv = qrow[d];
    } else {
        long p = pos[s];
        int dd = d - 128;
        float cv = cosT[p * 64 + dd], sv = sinT[p * 64 + dd];
        float val;
        if (dd < 32) val = bf2f(qrow[128 + 2 * dd]) * cv - bf2f(qrow[128 + 2 * dd + 1]) * sv;
        else { int jj = dd - 32; val = bf2f(qrow[128 + 2 * jj + 1]) * cv + bf2f(qrow[128 + 2 * jj]) * sv; }
        outv = f2bf(val);
    }
    Qb[((long)h * 2048 + s) * 192 + d] = outv;
}

// ---------------- K-nope copy + V transpose (single pass over kv, bf16 in) ----------------
__global__ __launch_bounds__(256) void build_kv2(const u16* __restrict__ kv, u16* __restrict__ Kb,
                                                 u16* __restrict__ Vt) {
    __shared__ u16 Ls[128][72];
    const int h = blockIdx.y, s0 = blockIdx.x * 64;
    const int tid = threadIdx.x;
#pragma unroll
    for (int i = 0; i < 8; ++i) {
        int u = i * 256 + tid;
        int r = u >> 5, c8 = (u & 31) * 8;
        short8 x = *(const short8*)(kv + (long)(s0 + r) * 4096 + h * 256 + c8);
        if (c8 < 128) {
            *(short8*)(Kb + ((long)h * 2048 + s0 + r) * 192 + c8) = x;
        } else {
#pragma unroll
            for (int j = 0; j < 8; ++j) {
                int d = c8 - 128 + j;
                Ls[d][r ^ (((d >> 3) & 7) << 3)] = (u16)x[j];
            }
        }
    }
    __syncthreads();
#pragma unroll
    for (int i = 0; i < 8; ++i) {
        int u = i * 256 + tid;
        int d = u >> 4, s4 = (u & 15) * 4;
        int swz = ((d >> 3) & 7) << 3;
        ushort4_t v;
        v.x = Ls[d][(s4 + 0) ^ swz]; v.y = Ls[d][(s4 + 1) ^ swz];
        v.z = Ls[d][(s4 + 2) ^ swz]; v.w = Ls[d][(s4 + 3) ^ swz];
        *(ushort4_t*)(Vt + ((long)h * 128 + d) * 2048 + s0 + s4) = v;
    }
}

// ---------------- causal flash attention (R9 structure + K row-XOR swizzle) ----------------
// 256 blocks x 512 thr. 8 waves = 2 KV-splits x 4 wave-pairs, 16 q-rows/wave.
// Pair-balanced q-tiles (pi, 31-pi) -> uniform 33 iters. Double-buffered K/V, 1 barrier/iter.
// K LDS: stride 192, c8 ^= (r&7) swizzle -> reads hit all 32 banks (2 lanes each, free).
__global__ __launch_bounds__(512) void attn_fwd(const u16* __restrict__ Qb, const u16* __restrict__ Kb,
                                                const u16* __restrict__ Vt, u16* __restrict__ Ao) {
    // [0,49152):      Ks[2 spl][2 buf][32][192] u16 (row-XOR swizzled)
    // [49152,81920):  Vs[2 spl][2 buf][4096] u16 (XOR-swizzled V^T)
    // [81920,92160):  Ps[8 wave][16][40] u16
    // [92160,92672):  ML float[64][2]
    // Ob alias [0,32768): float[64][128]
    __shared__ __align__(16) char smem[92672];

    const int b = blockIdx.x;
    const int h = (b & 7) * 2 + ((b >> 3) & 1);
    const int pi = b >> 4;
    const int tid = threadIdx.x;
    const int wid = tid >> 6, lane = tid & 63;
    const int lm = lane & 15, lk = lane >> 4;
    const int s = wid >> 2, wp = wid & 3;
    const int t256 = tid & 255;

    u16* Ks0 = (u16*)smem + s * 12288;           // two buffers of [32][192]
    u16* Vs0 = (u16*)(smem + 49152) + s * 8192;  // two buffers of [4096]
    u16* PsW = (u16*)(smem + 81920) + wid * 640;
    float* ML = (float*)(smem + 92160);
    float* Ob = (float*)smem;

    const u16* Kh = Kb + (long)h * 2048 * 192;
    const u16* Vh = Vt + (long)h * 128 * 2048;

    short8 bones = {};
    if (lm == 0) {
#pragma unroll
        for (int j = 0; j < 8; ++j) bones[j] = (short)0x3F80;   // bf16 1.0
    }
    const float C2 = 0.104117548f;   // 192^-0.5 * log2(e)

    for (int half = 0; half < 2; ++half) {
        const int qi = half ? (31 - pi) : pi;
        const int q0 = qi * 64;
        const int nt = 2 * qi + 2;
        const int niter = qi + 1;

        // Q fragments: 16 rows per wave
        short8 qf[6];
        const u16* qbase = Qb + ((long)h * 2048 + q0 + wp * 16 + lm) * 192;
#pragma unroll
        for (int kf = 0; kf < 6; ++kf) qf[kf] = *(const short8*)(qbase + kf * 32 + lk * 8);

        f32x4 o[8] = {};
        f32x4 o9 = {};
        float mrow[4] = {-1e30f, -1e30f, -1e30f, -1e30f};

        short8 kreg[3], vreg[2];
        // prologue: stage tile ts = s into buffer 0
        {
            const long k0 = s * 32;
#pragma unroll
            for (int i = 0; i < 3; ++i) {
                int idx = i * 256 + t256; int r = idx / 24, c = (idx % 24) * 8;
                kreg[i] = *(const short8*)(Kh + (k0 + r) * 192 + c);
            }
#pragma unroll
            for (int i = 0; i < 2; ++i) {
                int idx = i * 256 + t256; int dv = idx >> 2, kvb = idx & 3;
                vreg[i] = *(const short8*)(Vh + (long)dv * 2048 + k0 + kvb * 8);
            }
#pragma unroll
            for (int i = 0; i < 3; ++i) {
                int idx = i * 256 + t256; int r = idx / 24, c8 = idx % 24;
                *(short8*)&Ks0[r * 192 + ((c8 ^ (r & 7)) << 3)] = kreg[i];
            }
#pragma unroll
            for (int i = 0; i < 2; ++i) {
                int idx = i * 256 + t256; int dv = idx >> 2, kvb = idx & 3;
                *(short8*)&Vs0[kvb * 1024 + ((dv * 8) ^ (kvb * 16))] = vreg[i];
            }
        }
        __syncthreads();

        int cur = 0;
        for (int it = 0; it < niter; ++it) {
            const int ts = 2 * it + s;
            const int k0 = ts * 32;
            const bool more = (it + 1 < niter);

            // issue next tile's global loads early (latency hides under compute)
            if (more) {
                const long k0n = (long)(ts + 2) * 32;
#pragma unroll
                for (int i = 0; i < 3; ++i) {
                    int idx = i * 256 + t256; int r = idx / 24, c = (idx % 24) * 8;
                    kreg[i] = *(const short8*)(Kh + (k0n + r) * 192 + c);
                }
#pragma unroll
                for (int i = 0; i < 2; ++i) {
                    int idx = i * 256 + t256; int dv = idx >> 2, kvb = idx & 3;
                    vreg[i] = *(const short8*)(Vh + (long)dv * 2048 + k0n + kvb * 8);
                }
            }

            const u16* KsC = Ks0 + cur * 6144;
            const u16* VsC = Vs0 + cur * 4096;

            // S = Q K^T  (swizzled K reads: bank = 4*((kf*4+lk)^lm) -> conflict-free)
            f32x4 sfr[2] = {};
#pragma unroll
            for (int n = 0; n < 2; ++n)
#pragma unroll
                for (int kf = 0; kf < 6; ++kf) {
                    short8 kb = *(const short8*)&KsC[(n * 16 + lm) * 192 + (((kf * 4 + lk) ^ (lm & 7)) << 3)];
                    sfr[n] = __builtin_amdgcn_mfma_f32_16x16x32_bf16(qf[kf], kb, sfr[n], 0, 0, 0);
                }

            float sv[2][4];
            const bool bt = (ts >= nt - 2);
#pragma unroll
            for (int n = 0; n < 2; ++n)
#pragma unroll
                for (int r = 0; r < 4; ++r) {
                    float val = sfr[n][r] * C2;
                    if (bt && (k0 + n * 16 + lm > q0 + wp * 16 + lk * 4 + r)) val = -1e30f;
                    sv[n][r] = val;
                }

            // online softmax (base-2), DPP row-max, deferred-max rescale
            float pmax[4];
#pragma unroll
            for (int r = 0; r < 4; ++r)
                pmax[r] = rmax16(fmaxf(sv[0][r], sv[1][r]));
            bool need = (pmax[0] > mrow[0] + 8.f) || (pmax[1] > mrow[1] + 8.f) ||
                        (pmax[2] > mrow[2] + 8.f) || (pmax[3] > mrow[3] + 8.f);
            if (__any(need)) {
#pragma unroll
                for (int r = 0; r < 4; ++r) {
                    float mnew = fmaxf(mrow[r], pmax[r]);
                    float alpha = fexp2(mrow[r] - mnew);
                    mrow[r] = mnew;
#pragma unroll
                    for (int d = 0; d < 8; ++d) o[d][r] *= alpha;
                    o9[r] *= alpha;
                }
            }
            // P -> LDS via packed bf16 converts
#pragma unroll
            for (int n = 0; n < 2; ++n) {
                float p0 = fexp2(sv[n][0] - mrow[0]);
                float p1 = fexp2(sv[n][1] - mrow[1]);
                float p2 = fexp2(sv[n][2] - mrow[2]);
                float p3 = fexp2(sv[n][3] - mrow[3]);
                unsigned pk01 = cvtpk_bf16(p0, p1);
                unsigned pk23 = cvtpk_bf16(p2, p3);
                int rb = (lk * 4) * 40 + n * 16 + lm;
                PsW[rb]       = (u16)pk01;
                PsW[rb + 40]  = (u16)(pk01 >> 16);
                PsW[rb + 80]  = (u16)pk23;
                PsW[rb + 120] = (u16)(pk23 >> 16);
            }

            // O += P V (ones-column accumulates l into o9)
            short8 pf = *(const short8*)&PsW[lm * 40 + lk * 8];
#pragma unroll
            for (int d = 0; d < 8; ++d) {
                short8 vf = *(const short8*)&VsC[lk * 1024 + (((d * 16 + lm) * 8) ^ (lk * 16))];
                o[d] = __builtin_amdgcn_mfma_f32_16x16x32_bf16(pf, vf, o[d], 0, 0, 0);
            }
            o9 = __builtin_amdgcn_mfma_f32_16x16x32_bf16(pf, bones, o9, 0, 0, 0);

            // write next tile into the other buffer, then a single barrier
            if (more) {
                u16* KsN = Ks0 + (cur ^ 1) * 6144;
                u16* VsN = Vs0 + (cur ^ 1) * 4096;
#pragma unroll
                for (int i = 0; i < 3; ++i) {
                    int idx = i * 256 + t256; int r = idx / 24, c8 = idx % 24;
                    *(short8*)&KsN[r * 192 + ((c8 ^ (r & 7)) << 3)] = kreg[i];
                }
#pragma unroll
                for (int i = 0; i < 2; ++i) {
                    int idx = i * 256 + t256; int dv = idx >> 2, kvb = idx & 3;
                    *(short8*)&VsN[kvb * 1024 + ((dv * 8) ^ (kvb * 16))] = vreg[i];
                }
            }
            __syncthreads();
            cur ^= 1;
        }

        // ---- combine splits through LDS ----
        if (s == 1) {
#pragma unroll
            for (int d = 0; d < 8; ++d)
#pragma unroll
                for (int r = 0; r < 4; ++r)
                    Ob[(wp * 16 + lk * 4 + r) * 128 + d * 16 + lm] = o[d][r];
            if (lm == 0) {
#pragma unroll
                for (int r = 0; r < 4; ++r) {
                    int row = wp * 16 + lk * 4 + r;
                    ML[row * 2 + 0] = mrow[r];
                    ML[row * 2 + 1] = o9[r];
                }
            }
        }
        __syncthreads();
        if (s == 0) {
            float e0[4], e1[4], invl[4];
#pragma unroll
            for (int r = 0; r < 4; ++r) {
                int row = wp * 16 + lk * 4 + r;
                float m1 = ML[row * 2 + 0];
                float l1 = ML[row * 2 + 1];
                float l0 = __shfl(o9[r], lane & 48);
                float M = fmaxf(mrow[r], m1);
                e0[r] = fexp2(mrow[r] - M);
                e1[r] = fexp2(m1 - M);
                invl[r] = 1.f / (l0 * e0[r] + l1 * e1[r]);
            }
#pragma unroll
            for (int d = 0; d < 8; ++d)
#pragma unroll
                for (int r = 0; r < 4; ++r) {
                    int row = wp * 16 + lk * 4 + r;
                    float val = (o[d][r] * e0[r] +
                                 Ob[row * 128 + d * 16 + lm] * e1[r]) * invl[r];
                    Ao[((long)q0 + row) * 2048 + h * 128 + d * 16 + lm] = f2bf(val);
                }
        }
        __syncthreads();   // protect LDS before next half's staging
    }
}

// ---------------- host launch ----------------
extern "C" void kernel_launch(void* const* d_in, const int* in_sizes, int n_in,
                              void* d_out, int out_size, void* d_ws, size_t ws_size,
                              hipStream_t stream) {
    (void)in_sizes; (void)n_in; (void)out_size; (void)ws_size;
    const float* hidden  = (const float*)d_in[0];
    const float* q_a_w   = (const float*)d_in[1];
    const float* q_a_ln  = (const float*)d_in[2];
    const float* q_b_w   = (const float*)d_in[3];
    const float* kv_a_w  = (const float*)d_in[4];
    const float* kv_a_ln = (const float*)d_in[5];
    const float* kv_b_w  = (const float*)d_in[6];
    const float* o_w     = (const float*)d_in[7];
    const float* cosT    = (const float*)d_in[8];
    const float* sinT    = (const float*)d_in[9];
    const int*   pos     = (const int*)d_in[11];

    char* ws = (char*)d_ws;
    // persistent zone
    u16* o_w_bf   = (u16*)(ws + 0);          // 2048x2048
    u16* qb_w_bf  = (u16*)(ws + 8388608);    // 3072x1536
    u16* kvb_w_bf = (u16*)(ws + 17825792);   // 4096x512
    u16* qn_bf    = (u16*)(ws + 22020096);   // 2048x1536
    u16* kvn_bf   = (u16*)(ws + 28311552);   // 2048x512
    u16* Qb       = (u16*)(ws + 30408704);   // 16x2048x192
    u16* Kb       = (u16*)(ws + 42991616);   // 16x2048x192
    u16* Vt       = (u16*)(ws + 55574528);   // 16x128x2048
    u16* aout_bf  = (u16*)(ws + 63963136);   // 2048x2048, ends 72351744
    // transient zone
    u16*   hid_bf    = (u16*)(ws + 72351744);   // 2048x2048 bf16
    u16*   qkva_w_bf = (u16*)(ws + 80740352);   // 2176x2048 bf16
    float* qkva_f    = (float*)(ws + 89653248); // 2048x2176 f32, ends 107479040
    u16*   q_f_bf    = (u16*)(ws + 72351744);   // 2048x3072 bf16 (reuses hid+part of qkva_w)
    u16*   kv_f_bf   = (u16*)(ws + 89653248);   // 2048x4096 bf16 (reuses qkva_f)

    // converts
    conv_multi<<<17920, 256, 0, stream>>>(
        hidden, hid_bf,    1048576L,
        q_a_w,  qkva_w_bf, 1835008L,
        q_b_w,  qb_w_bf,   3014656L,
        kv_b_w, kvb_w_bf,  3538944L,
        o_w,    o_w_bf,    4587520L);
    conv_pad<<<(640L*2048/4 + 255)/256, 256, 0, stream>>>(kv_a_w, qkva_w_bf + 1536L*2048, 576, 640L*2048/4, 512);

    // fused down-projection: [2048,2048] x [2176,2048]^T -> [2048,2176] f32
    gemm64_p3<float><<<dim3(17, 32), 256, 0, stream>>>(hid_bf, qkva_w_bf, qkva_f, 2048, 2176, 2048);

    // norms + k_pe rope
    rmsnorm_bf16<<<2048, 256, 0, stream>>>(qkva_f, q_a_ln, qn_bf, 2176, 1536, 1536);
    rmsnorm_bf16<<<2048, 256, 0, stream>>>(qkva_f + 1536, kv_a_ln, kvn_bf, 2176, 512, 512);
    rope_k<<<(2048*32)/256, 256, 0, stream>>>(qkva_f, pos, cosT, sinT, Kb);

    // up-projections (bf16 outputs)
    gemm64_p3<u16><<<dim3(24, 32), 256, 0, stream>>>(qn_bf, qb_w_bf, q_f_bf, 2048, 3072, 1536);
    gemm64_p3<u16><<<dim3(32, 32), 256, 0, stream>>>(kvn_bf, kvb_w_bf, kv_f_bf, 2048, 4096, 512);

    // assemble Q / K-nope+V^T
    build_q<<<(unsigned)((16L*2048*192 + 255)/256), 256, 0, stream>>>(q_f_bf, pos, cosT, sinT, Qb);
    build_kv2<<<dim3(32, 16), 256, 0, stream>>>(kv_f_bf, Kb, Vt);

    // attention (256 blocks x 512 threads)
    attn_fwd<<<256, 512, 0, stream>>>(Qb, Kb, Vt, aout_bf);

    // output projection -> d_out (f32)
    gemm64_p3<float><<<dim3(16, 32), 256, 0, stream>>>(aout_bf, o_w_bf, (float*)d_out, 2048, 2048, 2048);
}

// Round 11
// 248.654 us; speedup vs baseline: 1.0186x; 1.0186x over previous
//
#include <hip/hip_runtime.h>
#include <stdint.h>

typedef unsigned short u16;
typedef __attribute__((ext_vector_type(8))) short short8;
typedef __attribute__((ext_vector_type(4))) float f32x4;
typedef __attribute__((ext_vector_type(4))) unsigned short ushort4_t;
typedef __attribute__((ext_vector_type(4))) float float4_t;

#define DEV_INLINE __device__ __forceinline__

DEV_INLINE u16 f2bf(float f) {
    union { float f; unsigned u; } x; x.f = f;
    unsigned u = x.u;
    unsigned r = (u + 0x7FFFu + ((u >> 16) & 1u)) >> 16;
    return (u16)r;
}

DEV_INLINE float bf2f(u16 b) {
    union { unsigned u; float f; } x; x.u = ((unsigned)b) << 16;
    return x.f;
}

DEV_INLINE float fexp2(float x) {
    float r;
    asm("v_exp_f32 %0, %1" : "=v"(r) : "v"(x));
    return r;
}

DEV_INLINE unsigned cvtpk_bf16(float lo, float hi) {
    unsigned r;
    asm("v_cvt_pk_bf16_f32 %0, %1, %2" : "=v"(r) : "v"(lo), "v"(hi));
    return r;
}

template <int CTRL>
DEV_INLINE float dppmax(float x) {
    union { float f; int i; } u; u.f = x;
    int y = __builtin_amdgcn_update_dpp(u.i, u.i, CTRL, 0xf, 0xf, true);
    union { int i; float f; } v; v.i = y;
    return fmaxf(x, v.f);
}

// max across each 16-lane group, no LDS
DEV_INLINE float rmax16(float x) {
    x = dppmax<0xB1>(x);    // quad_perm xor 1
    x = dppmax<0x4E>(x);    // quad_perm xor 2
    x = dppmax<0x141>(x);   // row_half_mirror (xor 7)
    x = dppmax<0x140>(x);   // row_mirror (xor 15)
    return x;
}

// ---------------- fused convert (5 plain f32->bf16 segments) ----------------
__global__ void conv_multi(const float* __restrict__ s0, u16* __restrict__ d0, long e0,
                           const float* __restrict__ s1, u16* __restrict__ d1, long e1,
                           const float* __restrict__ s2, u16* __restrict__ d2, long e2,
                           const float* __restrict__ s3, u16* __restrict__ d3, long e3,
                           const float* __restrict__ s4, u16* __restrict__ d4, long e4) {
    long i = (long)blockIdx.x * 256 + threadIdx.x;
    const float* s; u16* d; long base;
    if      (i < e0) { s = s0; d = d0; base = 0; }
    else if (i < e1) { s = s1; d = d1; base = e0; }
    else if (i < e2) { s = s2; d = d2; base = e1; }
    else if (i < e3) { s = s3; d = d3; base = e2; }
    else if (i < e4) { s = s4; d = d4; base = e3; }
    else return;
    long j = i - base;
    float4_t v = ((const float4_t*)s)[j];
    ushort4_t o;
    o.x = f2bf(v.x); o.y = f2bf(v.y); o.z = f2bf(v.z); o.w = f2bf(v.w);
    ((ushort4_t*)d)[j] = o;
}

__global__ void conv_pad(const float* __restrict__ in, u16* __restrict__ out,
                         int rows_valid, long n4, int cols4) {
    long i = (long)blockIdx.x * blockDim.x + threadIdx.x;
    if (i >= n4) return;
    long row = i / cols4;
    ushort4_t o; o.x = 0; o.y = 0; o.z = 0; o.w = 0;
    if (row < rows_valid) {
        float4_t v = ((const float4_t*)in)[i];
        o.x = f2bf(v.x); o.y = f2bf(v.y); o.z = f2bf(v.z); o.w = f2bf(v.w);
    }
    ((ushort4_t*)out)[i] = o;
}

// ---------------- add two f32 partials ----------------
__global__ void add2_f32(const float* __restrict__ a, const float* __restrict__ b,
                         float* __restrict__ c, long n4) {
    long i = (long)blockIdx.x * 256 + threadIdx.x;
    if (i >= n4) return;
    float4_t x = ((const float4_t*)a)[i];
    float4_t y = ((const float4_t*)b)[i];
    x.x += y.x; x.y += y.y; x.z += y.z; x.w += y.w;
    ((float4_t*)c)[i] = x;
}

#define BK 32

DEV_INLINE void gload16(const u16* g, u16* l) {
    __builtin_amdgcn_global_load_lds((const __attribute__((address_space(1))) unsigned int*)g,
                                     (__attribute__((address_space(3))) unsigned int*)l,
                                     16, 0, 0);
}

// ---------------- GEMM 64x128 double-buffered ----------------
template <typename OT>
__global__ __launch_bounds__(256) void gemm64_db(const u16* __restrict__ A, const u16* __restrict__ B,
                                                 OT* __restrict__ C, int M, int N, int K) {
    __shared__ u16 As[2][64 * BK];
    __shared__ u16 Bs[2][128 * BK];
    const int tid = threadIdx.x;
    const int wid = tid >> 6, lane = tid & 63;
    const int lm = lane & 15, lk = lane >> 4;
    const long bm = (long)blockIdx.y * 64, bn = (long)blockIdx.x * 128;

    f32x4 acc[4][2] = {};

    const int rowS = lane >> 2;
    const int colS = ((lane & 3) ^ ((lane >> 3) & 3)) * 8;
    const int cs = (lm >> 1) & 3;
    const u16* Ag = A + (bm + wid * 16 + rowS) * (long)K + colS;
    const u16* Bg = B + (bn + wid * 32 + rowS) * (long)K + colS;
    const int aoff = wid * 16 * BK;
    const int boff = wid * 32 * BK;

    gload16(Ag, &As[0][aoff]);
    gload16(Bg, &Bs[0][boff]);
    gload16(Bg + 16 * (long)K, &Bs[0][boff + 16 * BK]);
    __syncthreads();

    int cur = 0;
    for (int k0 = 0; k0 < K; k0 += BK) {
        if (k0 + BK < K) {
            gload16(Ag + k0 + BK, &As[cur ^ 1][aoff]);
            gload16(Bg + k0 + BK, &Bs[cur ^ 1][boff]);
            gload16(Bg + 16 * (long)K + k0 + BK, &Bs[cur ^ 1][boff + 16 * BK]);
        }
        short8 af[4], bfr[2];
#pragma unroll
        for (int m = 0; m < 4; ++m)
            af[m] = *(const short8*)&As[cur][(m * 16 + lm) * BK + (lk ^ cs) * 8];
#pragma unroll
        for (int n = 0; n < 2; ++n)
            bfr[n] = *(const short8*)&Bs[cur][(wid * 32 + n * 16 + lm) * BK + (lk ^ cs) * 8];
#pragma unroll
        for (int m = 0; m < 4; ++m)
#pragma unroll
            for (int n = 0; n < 2; ++n)
                acc[m][n] = __builtin_amdgcn_mfma_f32_16x16x32_bf16(af[m], bfr[n], acc[m][n], 0, 0, 0);
        __syncthreads();
        cur ^= 1;
    }

#pragma unroll
    for (int m = 0; m < 4; ++m)
#pragma unroll
        for (int n = 0; n < 2; ++n)
#pragma unroll
            for (int r = 0; r < 4; ++r) {
                long idx = (bm + m * 16 + lk * 4 + r) * (long)N + bn + wid * 32 + n * 16 + lm;
                if constexpr (sizeof(OT) == 4) C[idx] = acc[m][n][r];
                else                           C[idx] = f2bf(acc[m][n][r]);
            }
}

// ---------------- GEMM 128x128 double-buffered, optional split-K (partial buffers) ----------------
// SPLITK>1: blockIdx.z selects K-chunk; C_partial = C + z*M*N (no atomics, deterministic).
template <typename OT, int SPLITK>
__global__ __launch_bounds__(256) void gemm128_db(const u16* __restrict__ A, const u16* __restrict__ B,
                                                  OT* __restrict__ C, int M, int N, int K) {
    __shared__ u16 As[2][128 * BK];
    __shared__ u16 Bs[2][128 * BK];
    const int tid = threadIdx.x;
    const int wid = tid >> 6, lane = tid & 63;
    const int lm = lane & 15, lk = lane >> 4;
    const int wr = wid >> 1, wc = wid & 1;
    const long bm = (long)blockIdx.y * 128, bn = (long)blockIdx.x * 128;
    const int Kh = K / SPLITK;
    const long kbase = (long)blockIdx.z * Kh;
    OT* Cp = C + (long)blockIdx.z * M * (long)N;

    f32x4 acc[4][4] = {};

    const int rowS = lane >> 2;
    const int colS = ((lane & 3) ^ ((lane >> 3) & 3)) * 8;
    const int cs = (lm >> 1) & 3;
    const u16* Ag = A + (bm + wid * 16 + rowS) * (long)K + kbase + colS;
    const u16* Bg = B + (bn + wid * 16 + rowS) * (long)K + kbase + colS;
    const int off0 = wid * 512;
    const int off1 = off0 + 64 * 32;

    gload16(Ag, &As[0][off0]);
    gload16(Ag + 64 * (long)K, &As[0][off1]);
    gload16(Bg, &Bs[0][off0]);
    gload16(Bg + 64 * (long)K, &Bs[0][off1]);
    __syncthreads();

    int cur = 0;
    for (int k0 = 0; k0 < Kh; k0 += BK) {
        if (k0 + BK < Kh) {
            gload16(Ag + k0 + BK, &As[cur ^ 1][off0]);
            gload16(Ag + 64 * (long)K + k0 + BK, &As[cur ^ 1][off1]);
            gload16(Bg + k0 + BK, &Bs[cur ^ 1][off0]);
            gload16(Bg + 64 * (long)K + k0 + BK, &Bs[cur ^ 1][off1]);
        }
        short8 af[4], bfr[4];
#pragma unroll
        for (int m = 0; m < 4; ++m)
            af[m] = *(const short8*)&As[cur][(wr * 64 + m * 16 + lm) * BK + (lk ^ cs) * 8];
#pragma unroll
        for (int n = 0; n < 4; ++n)
            bfr[n] = *(const short8*)&Bs[cur][(wc * 64 + n * 16 + lm) * BK + (lk ^ cs) * 8];
#pragma unroll
        for (int m = 0; m < 4; ++m)
#pragma unroll
            for (int n = 0; n < 4; ++n)
                acc[m][n] = __builtin_amdgcn_mfma_f32_16x16x32_bf16(af[m], bfr[n], acc[m][n], 0, 0, 0);
        __syncthreads();
        cur ^= 1;
    }

#pragma unroll
    for (int m = 0; m < 4; ++m)
#pragma unroll
        for (int n = 0; n < 4; ++n)
#pragma unroll
            for (int r = 0; r < 4; ++r) {
                long idx = (bm + wr * 64 + m * 16 + lk * 4 + r) * (long)N + bn + wc * 64 + n * 16 + lm;
                if constexpr (sizeof(OT) == 4) Cp[idx] = acc[m][n][r];
                else                           Cp[idx] = f2bf(acc[m][n][r]);
            }
}

// ---------------- RMSNorm (f32 in, bf16 out) ----------------
__global__ __launch_bounds__(256) void rmsnorm_bf16(const float* __restrict__ in, const float* __restrict__ w,
                                                    u16* __restrict__ out, int ldin, int ldout, int ncols) {
    const int row = blockIdx.x, tid = threadIdx.x;
    const float* x = in + (long)row * ldin;
    float ss = 0.f;
    for (int c = tid; c < ncols; c += 256) { float v = x[c]; ss = fmaf(v, v, ss); }
#pragma unroll
    for (int off = 32; off > 0; off >>= 1) ss += __shfl_down(ss, off);
    __shared__ float part[4];
    if ((tid & 63) == 0) part[tid >> 6] = ss;
    __syncthreads();
    float tot = part[0] + part[1] + part[2] + part[3];
    float rs = rsqrtf(tot / (float)ncols + 1e-6f);
    for (int c = tid; c < ncols; c += 256) out[(long)row * ldout + c] = f2bf(x[c] * rs * w[c]);
}

// ---------------- k_pe RoPE -> K[:, :, 128:192] for all heads ----------------
__global__ void rope_k(const float* __restrict__ ckv, const int* __restrict__ pos,
                       const float* __restrict__ cosT, const float* __restrict__ sinT,
                       u16* __restrict__ Kb) {
    int idx = blockIdx.x * 256 + threadIdx.x;
    if (idx >= 2048 * 32) return;
    int s = idx >> 5, j = idx & 31;
    long p = pos[s];
    const float* row = ckv + (long)s * 2176 + 2048;
    float x0 = row[2 * j], x1 = row[2 * j + 1];
    float c0 = cosT[p * 64 + j],      s0 = sinT[p * 64 + j];
    float c1 = cosT[p * 64 + 32 + j], s1 = sinT[p * 64 + 32 + j];
    u16 o0 = f2bf(x0 * c0 - x1 * s0);
    u16 o1 = f2bf(x1 * c1 + x0 * s1);
#pragma unroll
    for (int h = 0; h < 16; ++h) {
        u16* kr = Kb + ((long)h * 2048 + s) * 192 + 128;
        kr[j] = o0; kr[32 + j] = o1;
    }
}

// ---------------- assemble Q (bf16 in, RoPE on last 64 dims) ----------------
__global__ void build_q(const u16* __restrict__ q, const int* __restrict__ pos,
                        const float* __restrict__ cosT, const float* __restrict__ sinT,
                        u16* __restrict__ Qb) {
    long idx = (long)blockIdx.x * 256 + threadIdx.x;
    if (idx >= 16L * 2048 * 192) return;
    int d = (int)(idx % 192);
    int s = (int)((idx / 192) % 2048);
    int h = (int)(idx / (192L * 2048));
    const u16* qrow = q + (long)s * 3072 + h * 192;
    u16 outv;
    if (d < 128) {
        outv = qrow[d];
    } else {
        long p = pos[s];
        int dd = d - 128;
        float cv = cosT[p * 64 + dd], sv = sinT[p * 64 + dd];
        float val;
        if (dd < 32) val = bf2f(qrow[128 + 2 * dd]) * cv - bf2f(qrow[128 + 2 * dd + 1]) * sv;
        else { int jj = dd - 32; val = bf2f(qrow[128 + 2 * jj + 1]) * cv + bf2f(qrow[128 + 2 * jj]) * sv; }
        outv = f2bf(val);
    }
    Qb[((long)h * 2048 + s) * 192 + d] = outv;
}

// ---------------- K-nope copy + V transpose (single pass over kv, bf16 in) ----------------
__global__ __launch_bounds__(256) void build_kv2(const u16* __restrict__ kv, u16* __restrict__ Kb,
                                                 u16* __restrict__ Vt) {
    __shared__ u16 Ls[128][72];
    const int h = blockIdx.y, s0 = blockIdx.x * 64;
    const int tid = threadIdx.x;
#pragma unroll
    for (int i = 0; i < 8; ++i) {
        int u = i * 256 + tid;
        int r = u >> 5, c8 = (u & 31) * 8;
        short8 x = *(const short8*)(kv + (long)(s0 + r) * 4096 + h * 256 + c8);
        if (c8 < 128) {
            *(short8*)(Kb + ((long)h * 2048 + s0 + r) * 192 + c8) = x;
        } else {
#pragma unroll
            for (int j = 0; j < 8; ++j) {
                int d = c8 - 128 + j;
                Ls[d][r ^ (((d >> 3) & 7) << 3)] = (u16)x[j];
            }
        }
    }
    __syncthreads();
#pragma unroll
    for (int i = 0; i < 8; ++i) {
        int u = i * 256 + tid;
        int d = u >> 4, s4 = (u & 15) * 4;
        int swz = ((d >> 3) & 7) << 3;
        ushort4_t v;
        v.x = Ls[d][(s4 + 0) ^ swz]; v.y = Ls[d][(s4 + 1) ^ swz];
        v.z = Ls[d][(s4 + 2) ^ swz]; v.w = Ls[d][(s4 + 3) ^ swz];
        *(ushort4_t*)(Vt + ((long)h * 128 + d) * 2048 + s0 + s4) = v;
    }
}

// ---------------- causal flash attention (unchanged from R10) ----------------
__global__ __launch_bounds__(512) void attn_fwd(const u16* __restrict__ Qb, const u16* __restrict__ Kb,
                                                const u16* __restrict__ Vt, u16* __restrict__ Ao) {
    __shared__ __align__(16) char smem[92672];

    const int b = blockIdx.x;
    const int h = (b & 7) * 2 + ((b >> 3) & 1);
    const int pi = b >> 4;
    const int tid = threadIdx.x;
    const int wid = tid >> 6, lane = tid & 63;
    const int lm = lane & 15, lk = lane >> 4;
    const int s = wid >> 2, wp = wid & 3;
    const int t256 = tid & 255;

    u16* Ks0 = (u16*)smem + s * 12288;
    u16* Vs0 = (u16*)(smem + 49152) + s * 8192;
    u16* PsW = (u16*)(smem + 81920) + wid * 640;
    float* ML = (float*)(smem + 92160);
    float* Ob = (float*)smem;

    const u16* Kh = Kb + (long)h * 2048 * 192;
    const u16* Vh = Vt + (long)h * 128 * 2048;

    short8 bones = {};
    if (lm == 0) {
#pragma unroll
        for (int j = 0; j < 8; ++j) bones[j] = (short)0x3F80;
    }
    const float C2 = 0.104117548f;   // 192^-0.5 * log2(e)

    for (int half = 0; half < 2; ++half) {
        const int qi = half ? (31 - pi) : pi;
        const int q0 = qi * 64;
        const int nt = 2 * qi + 2;
        const int niter = qi + 1;

        short8 qf[6];
        const u16* qbase = Qb + ((long)h * 2048 + q0 + wp * 16 + lm) * 192;
#pragma unroll
        for (int kf = 0; kf < 6; ++kf) qf[kf] = *(const short8*)(qbase + kf * 32 + lk * 8);

        f32x4 o[8] = {};
        f32x4 o9 = {};
        float mrow[4] = {-1e30f, -1e30f, -1e30f, -1e30f};

        short8 kreg[3], vreg[2];
        {
            const long k0 = s * 32;
#pragma unroll
            for (int i = 0; i < 3; ++i) {
                int idx = i * 256 + t256; int r = idx / 24, c = (idx % 24) * 8;
                kreg[i] = *(const short8*)(Kh + (k0 + r) * 192 + c);
            }
#pragma unroll
            for (int i = 0; i < 2; ++i) {
                int idx = i * 256 + t256; int dv = idx >> 2, kvb = idx & 3;
                vreg[i] = *(const short8*)(Vh + (long)dv * 2048 + k0 + kvb * 8);
            }
#pragma unroll
            for (int i = 0; i < 3; ++i) {
                int idx = i * 256 + t256; int r = idx / 24, c8 = idx % 24;
                *(short8*)&Ks0[r * 192 + ((c8 ^ (r & 7)) << 3)] = kreg[i];
            }
#pragma unroll
            for (int i = 0; i < 2; ++i) {
                int idx = i * 256 + t256; int dv = idx >> 2, kvb = idx & 3;
                *(short8*)&Vs0[kvb * 1024 + ((dv * 8) ^ (kvb * 16))] = vreg[i];
            }
        }
        __syncthreads();

        int cur = 0;
        for (int it = 0; it < niter; ++it) {
            const int ts = 2 * it + s;
            const int k0 = ts * 32;
            const bool more = (it + 1 < niter);

            if (more) {
                const long k0n = (long)(ts + 2) * 32;
#pragma unroll
                for (int i = 0; i < 3; ++i) {
                    int idx = i * 256 + t256; int r = idx / 24, c = (idx % 24) * 8;
                    kreg[i] = *(const short8*)(Kh + (k0n + r) * 192 + c);
                }
#pragma unroll
                for (int i = 0; i < 2; ++i) {
                    int idx = i * 256 + t256; int dv = idx >> 2, kvb = idx & 3;
                    vreg[i] = *(const short8*)(Vh + (long)dv * 2048 + k0n + kvb * 8);
                }
            }

            const u16* KsC = Ks0 + cur * 6144;
            const u16* VsC = Vs0 + cur * 4096;

            f32x4 sfr[2] = {};
#pragma unroll
            for (int n = 0; n < 2; ++n)
#pragma unroll
                for (int kf = 0; kf < 6; ++kf) {
                    short8 kb = *(const short8*)&KsC[(n * 16 + lm) * 192 + (((kf * 4 + lk) ^ (lm & 7)) << 3)];
                    sfr[n] = __builtin_amdgcn_mfma_f32_16x16x32_bf16(qf[kf], kb, sfr[n], 0, 0, 0);
                }

            float sv[2][4];
            const bool bt = (ts >= nt - 2);
#pragma unroll
            for (int n = 0; n < 2; ++n)
#pragma unroll
                for (int r = 0; r < 4; ++r) {
                    float val = sfr[n][r] * C2;
                    if (bt && (k0 + n * 16 + lm > q0 + wp * 16 + lk * 4 + r)) val = -1e30f;
                    sv[n][r] = val;
                }

            float pmax[4];
#pragma unroll
            for (int r = 0; r < 4; ++r)
                pmax[r] = rmax16(fmaxf(sv[0][r], sv[1][r]));
            bool need = (pmax[0] > mrow[0] + 8.f) || (pmax[1] > mrow[1] + 8.f) ||
                        (pmax[2] > mrow[2] + 8.f) || (pmax[3] > mrow[3] + 8.f);
            if (__any(need)) {
#pragma unroll
                for (int r = 0; r < 4; ++r) {
                    float mnew = fmaxf(mrow[r], pmax[r]);
                    float alpha = fexp2(mrow[r] - mnew);
                    mrow[r] = mnew;
#pragma unroll
                    for (int d = 0; d < 8; ++d) o[d][r] *= alpha;
                    o9[r] *= alpha;
                }
            }
#pragma unroll
            for (int n = 0; n < 2; ++n) {
                float p0 = fexp2(sv[n][0] - mrow[0]);
                float p1 = fexp2(sv[n][1] - mrow[1]);
                float p2 = fexp2(sv[n][2] - mrow[2]);
                float p3 = fexp2(sv[n][3] - mrow[3]);
                unsigned pk01 = cvtpk_bf16(p0, p1);
                unsigned pk23 = cvtpk_bf16(p2, p3);
                int rb = (lk * 4) * 40 + n * 16 + lm;
                PsW[rb]       = (u16)pk01;
                PsW[rb + 40]  = (u16)(pk01 >> 16);
                PsW[rb + 80]  = (u16)pk23;
                PsW[rb + 120] = (u16)(pk23 >> 16);
            }

            short8 pf = *(const short8*)&PsW[lm * 40 + lk * 8];
#pragma unroll
            for (int d = 0; d < 8; ++d) {
                short8 vf = *(const short8*)&VsC[lk * 1024 + (((d * 16 + lm) * 8) ^ (lk * 16))];
                o[d] = __builtin_amdgcn_mfma_f32_16x16x32_bf16(pf, vf, o[d], 0, 0, 0);
            }
            o9 = __builtin_amdgcn_mfma_f32_16x16x32_bf16(pf, bones, o9, 0, 0, 0);

            if (more) {
                u16* KsN = Ks0 + (cur ^ 1) * 6144;
                u16* VsN = Vs0 + (cur ^ 1) * 4096;
#pragma unroll
                for (int i = 0; i < 3; ++i) {
                    int idx = i * 256 + t256; int r = idx / 24, c8 = idx % 24;
                    *(short8*)&KsN[r * 192 + ((c8 ^ (r & 7)) << 3)] = kreg[i];
                }
#pragma unroll
                for (int i = 0; i < 2; ++i) {
                    int idx = i * 256 + t256; int dv = idx >> 2, kvb = idx & 3;
                    *(short8*)&VsN[kvb * 1024 + ((dv * 8) ^ (kvb * 16))] = vreg[i];
                }
            }
            __syncthreads();
            cur ^= 1;
        }

        if (s == 1) {
#pragma unroll
            for (int d = 0; d < 8; ++d)
#pragma unroll
                for (int r = 0; r < 4; ++r)
                    Ob[(wp * 16 + lk * 4 + r) * 128 + d * 16 + lm] = o[d][r];
            if (lm == 0) {
#pragma unroll
                for (int r = 0; r < 4; ++r) {
                    int row = wp * 16 + lk * 4 + r;
                    ML[row * 2 + 0] = mrow[r];
                    ML[row * 2 + 1] = o9[r];
                }
            }
        }
        __syncthreads();
        if (s == 0) {
            float e0[4], e1[4], invl[4];
#pragma unroll
            for (int r = 0; r < 4; ++r) {
                int row = wp * 16 + lk * 4 + r;
                float m1 = ML[row * 2 + 0];
                float l1 = ML[row * 2 + 1];
                float l0 = __shfl(o9[r], lane & 48);
                float M = fmaxf(mrow[r], m1);
                e0[r] = fexp2(mrow[r] - M);
                e1[r] = fexp2(m1 - M);
                invl[r] = 1.f / (l0 * e0[r] + l1 * e1[r]);
            }
#pragma unroll
            for (int d = 0; d < 8; ++d)
#pragma unroll
                for (int r = 0; r < 4; ++r) {
                    int row = wp * 16 + lk * 4 + r;
                    float val = (o[d][r] * e0[r] +
                                 Ob[row * 128 + d * 16 + lm] * e1[r]) * invl[r];
                    Ao[((long)q0 + row) * 2048 + h * 128 + d * 16 + lm] = f2bf(val);
                }
        }
        __syncthreads();
    }
}

// ---------------- host launch ----------------
extern "C" void kernel_launch(void* const* d_in, const int* in_sizes, int n_in,
                              void* d_out, int out_size, void* d_ws, size_t ws_size,
                              hipStream_t stream) {
    (void)in_sizes; (void)n_in; (void)out_size; (void)ws_size;
    const float* hidden  = (const float*)d_in[0];
    const float* q_a_w   = (const float*)d_in[1];
    const float* q_a_ln  = (const float*)d_in[2];
    const float* q_b_w   = (const float*)d_in[3];
    const float* kv_a_w  = (const float*)d_in[4];
    const float* kv_a_ln = (const float*)d_in[5];
    const float* kv_b_w  = (const float*)d_in[6];
    const float* o_w     = (const float*)d_in[7];
    const float* cosT    = (const float*)d_in[8];
    const float* sinT    = (const float*)d_in[9];
    const int*   pos     = (const int*)d_in[11];

    char* ws = (char*)d_ws;
    // persistent zone
    u16* o_w_bf   = (u16*)(ws + 0);          // 2048x2048
    u16* qb_w_bf  = (u16*)(ws + 8388608);    // 3072x1536
    u16* kvb_w_bf = (u16*)(ws + 17825792);   // 4096x512
    u16* qn_bf    = (u16*)(ws + 22020096);   // 2048x1536
    u16* kvn_bf   = (u16*)(ws + 28311552);   // 2048x512
    u16* Qb       = (u16*)(ws + 30408704);   // 16x2048x192
    u16* Kb       = (u16*)(ws + 42991616);   // 16x2048x192
    u16* Vt       = (u16*)(ws + 55574528);   // 16x128x2048
    u16* aout_bf  = (u16*)(ws + 63963136);   // 2048x2048, ends 72351744
    // transient zone
    u16*   hid_bf    = (u16*)(ws + 72351744);   // 2048x2048 bf16
    u16*   qkva_w_bf = (u16*)(ws + 80740352);   // 2176x2048 bf16
    float* qkva_f    = (float*)(ws + 89653248); // 2048x2176 f32, ends 107479040
    u16*   q_f_bf    = (u16*)(ws + 72351744);   // 2048x3072 bf16 (reuses hid+part of qkva_w)
    u16*   kv_f_bf   = (u16*)(ws + 89653248);   // 2048x4096 bf16 (reuses qkva_f)
    // o-proj split-K partials (reuse transient zone after kv_f dead... kv_f dies after build_kv2)
    float* op0       = (float*)(ws + 107479040); // 2048x2048 f32, ends 124256256
    float* op1       = (float*)(ws + 124256256); // 2048x2048 f32, ends 141033472

    // converts
    conv_multi<<<17920, 256, 0, stream>>>(
        hidden, hid_bf,    1048576L,
        q_a_w,  qkva_w_bf, 1835008L,
        q_b_w,  qb_w_bf,   3014656L,
        kv_b_w, kvb_w_bf,  3538944L,
        o_w,    o_w_bf,    4587520L);
    conv_pad<<<(640L*2048/4 + 255)/256, 256, 0, stream>>>(kv_a_w, qkva_w_bf + 1536L*2048, 576, 640L*2048/4, 512);

    // fused down-projection: [2048,2048] x [2176,2048]^T -> [2048,2176] f32 (544 blocks)
    gemm64_db<float><<<dim3(17, 32), 256, 0, stream>>>(hid_bf, qkva_w_bf, qkva_f, 2048, 2176, 2048);

    // norms + k_pe rope
    rmsnorm_bf16<<<2048, 256, 0, stream>>>(qkva_f, q_a_ln, qn_bf, 2176, 1536, 1536);
    rmsnorm_bf16<<<2048, 256, 0, stream>>>(qkva_f + 1536, kv_a_ln, kvn_bf, 2176, 512, 512);
    rope_k<<<(2048*32)/256, 256, 0, stream>>>(qkva_f, pos, cosT, sinT, Kb);

    // up-projections: 128x128 tile (384 / 512 blocks)
    gemm128_db<u16, 1><<<dim3(24, 16), 256, 0, stream>>>(qn_bf, qb_w_bf, q_f_bf, 2048, 3072, 1536);
    gemm128_db<u16, 1><<<dim3(32, 16), 256, 0, stream>>>(kvn_bf, kvb_w_bf, kv_f_bf, 2048, 4096, 512);

    // assemble Q / K-nope+V^T
    build_q<<<(unsigned)((16L*2048*192 + 255)/256), 256, 0, stream>>>(q_f_bf, pos, cosT, sinT, Qb);
    build_kv2<<<dim3(32, 16), 256, 0, stream>>>(kv_f_bf, Kb, Vt);

    // attention
    attn_fwd<<<256, 512, 0, stream>>>(Qb, Kb, Vt, aout_bf);

    // output projection: 128x128 split-K=2 -> two f32 partials (512 blocks), then add
    gemm128_db<float, 2><<<dim3(16, 16, 2), 256, 0, stream>>>(aout_bf, o_w_bf, op0, 2048, 2048, 2048);
    add2_f32<<<4096, 256, 0, stream>>>(op0, op1, (float*)d_out, 2048L*2048/4);
}

// Round 12
// 235.848 us; speedup vs baseline: 1.0739x; 1.0543x over previous
//
#include <hip/hip_runtime.h>
#include <stdint.h>

typedef unsigned short u16;
typedef __attribute__((ext_vector_type(8))) short short8;
typedef __attribute__((ext_vector_type(4))) float f32x4;
typedef __attribute__((ext_vector_type(4))) unsigned short ushort4_t;
typedef __attribute__((ext_vector_type(4))) float float4_t;

#define DEV_INLINE __device__ __forceinline__

DEV_INLINE u16 f2bf(float f) {
    union { float f; unsigned u; } x; x.f = f;
    unsigned u = x.u;
    unsigned r = (u + 0x7FFFu + ((u >> 16) & 1u)) >> 16;
    return (u16)r;
}

DEV_INLINE float bf2f(u16 b) {
    union { unsigned u; float f; } x; x.u = ((unsigned)b) << 16;
    return x.f;
}

DEV_INLINE float fexp2(float x) {
    float r;
    asm("v_exp_f32 %0, %1" : "=v"(r) : "v"(x));
    return r;
}

DEV_INLINE unsigned cvtpk_bf16(float lo, float hi) {
    unsigned r;
    asm("v_cvt_pk_bf16_f32 %0, %1, %2" : "=v"(r) : "v"(lo), "v"(hi));
    return r;
}

template <int CTRL>
DEV_INLINE float dppmaxf(float x) {
    union { float f; int i; } u; u.f = x;
    int y = __builtin_amdgcn_update_dpp(u.i, u.i, CTRL, 0xf, 0xf, true);
    union { int i; float f; } v; v.i = y;
    return fmaxf(x, v.f);
}

// exchange with neighbor lane (lane ^ 1)
DEV_INLINE float dpp_xor1(float x) {
    union { float f; int i; } u; u.f = x;
    int y = __builtin_amdgcn_update_dpp(u.i, u.i, 0xB1, 0xf, 0xf, true);
    union { int i; float f; } v; v.i = y;
    return v.f;
}

// max across each 16-lane group, no LDS
DEV_INLINE float rmax16(float x) {
    x = dppmaxf<0xB1>(x);    // quad_perm xor 1
    x = dppmaxf<0x4E>(x);    // quad_perm xor 2
    x = dppmaxf<0x141>(x);   // row_half_mirror (xor 7)
    x = dppmaxf<0x140>(x);   // row_mirror (xor 15)
    return x;
}

// ---------------- fused convert (5 plain f32->bf16 segments) ----------------
__global__ void conv_multi(const float* __restrict__ s0, u16* __restrict__ d0, long e0,
                           const float* __restrict__ s1, u16* __restrict__ d1, long e1,
                           const float* __restrict__ s2, u16* __restrict__ d2, long e2,
                           const float* __restrict__ s3, u16* __restrict__ d3, long e3,
                           const float* __restrict__ s4, u16* __restrict__ d4, long e4) {
    long i = (long)blockIdx.x * 256 + threadIdx.x;
    const float* s; u16* d; long base;
    if      (i < e0) { s = s0; d = d0; base = 0; }
    else if (i < e1) { s = s1; d = d1; base = e0; }
    else if (i < e2) { s = s2; d = d2; base = e1; }
    else if (i < e3) { s = s3; d = d3; base = e2; }
    else if (i < e4) { s = s4; d = d4; base = e3; }
    else return;
    long j = i - base;
    float4_t v = ((const float4_t*)s)[j];
    ushort4_t o;
    o.x = f2bf(v.x); o.y = f2bf(v.y); o.z = f2bf(v.z); o.w = f2bf(v.w);
    ((ushort4_t*)d)[j] = o;
}

__global__ void conv_pad(const float* __restrict__ in, u16* __restrict__ out,
                         int rows_valid, long n4, int cols4) {
    long i = (long)blockIdx.x * blockDim.x + threadIdx.x;
    if (i >= n4) return;
    long row = i / cols4;
    ushort4_t o; o.x = 0; o.y = 0; o.z = 0; o.w = 0;
    if (row < rows_valid) {
        float4_t v = ((const float4_t*)in)[i];
        o.x = f2bf(v.x); o.y = f2bf(v.y); o.z = f2bf(v.z); o.w = f2bf(v.w);
    }
    ((ushort4_t*)out)[i] = o;
}

#define BK 32

DEV_INLINE void gload16(const u16* g, u16* l) {
    __builtin_amdgcn_global_load_lds((const __attribute__((address_space(1))) unsigned int*)g,
                                     (__attribute__((address_space(3))) unsigned int*)l,
                                     16, 0, 0);
}

// ---------------- GEMM 64x128 double-buffered ----------------
template <typename OT>
__global__ __launch_bounds__(256) void gemm64_db(const u16* __restrict__ A, const u16* __restrict__ B,
                                                 OT* __restrict__ C, int M, int N, int K) {
    __shared__ u16 As[2][64 * BK];
    __shared__ u16 Bs[2][128 * BK];
    const int tid = threadIdx.x;
    const int wid = tid >> 6, lane = tid & 63;
    const int lm = lane & 15, lk = lane >> 4;
    const long bm = (long)blockIdx.y * 64, bn = (long)blockIdx.x * 128;

    f32x4 acc[4][2] = {};

    const int rowS = lane >> 2;
    const int colS = ((lane & 3) ^ ((lane >> 3) & 3)) * 8;
    const int cs = (lm >> 1) & 3;
    const u16* Ag = A + (bm + wid * 16 + rowS) * (long)K + colS;
    const u16* Bg = B + (bn + wid * 32 + rowS) * (long)K + colS;
    const int aoff = wid * 16 * BK;
    const int boff = wid * 32 * BK;

    gload16(Ag, &As[0][aoff]);
    gload16(Bg, &Bs[0][boff]);
    gload16(Bg + 16 * (long)K, &Bs[0][boff + 16 * BK]);
    __syncthreads();

    int cur = 0;
    for (int k0 = 0; k0 < K; k0 += BK) {
        if (k0 + BK < K) {
            gload16(Ag + k0 + BK, &As[cur ^ 1][aoff]);
            gload16(Bg + k0 + BK, &Bs[cur ^ 1][boff]);
            gload16(Bg + 16 * (long)K + k0 + BK, &Bs[cur ^ 1][boff + 16 * BK]);
        }
        short8 af[4], bfr[2];
#pragma unroll
        for (int m = 0; m < 4; ++m)
            af[m] = *(const short8*)&As[cur][(m * 16 + lm) * BK + (lk ^ cs) * 8];
#pragma unroll
        for (int n = 0; n < 2; ++n)
            bfr[n] = *(const short8*)&Bs[cur][(wid * 32 + n * 16 + lm) * BK + (lk ^ cs) * 8];
#pragma unroll
        for (int m = 0; m < 4; ++m)
#pragma unroll
            for (int n = 0; n < 2; ++n)
                acc[m][n] = __builtin_amdgcn_mfma_f32_16x16x32_bf16(af[m], bfr[n], acc[m][n], 0, 0, 0);
        __syncthreads();
        cur ^= 1;
    }

#pragma unroll
    for (int m = 0; m < 4; ++m)
#pragma unroll
        for (int n = 0; n < 2; ++n)
#pragma unroll
            for (int r = 0; r < 4; ++r) {
                long idx = (bm + m * 16 + lk * 4 + r) * (long)N + bn + wid * 32 + n * 16 + lm;
                if constexpr (sizeof(OT) == 4) C[idx] = acc[m][n][r];
                else                           C[idx] = f2bf(acc[m][n][r]);
            }
}

// ---------------- dual GEMM: q_b (Qb direct + RoPE) and kv_b in one launch ----------------
// blocks [0,768): q route:  [2048x1536] x [3072x1536]^T, epilogue -> Qb with interleaved RoPE
// blocks [768,1792): kv route: [2048x512] x [4096x512]^T -> kv_f (row-major bf16)
__global__ __launch_bounds__(256) void gemm_qkv(const u16* __restrict__ qnA, const u16* __restrict__ qbB,
                                                const u16* __restrict__ kvnA, const u16* __restrict__ kvbB,
                                                u16* __restrict__ Qb, u16* __restrict__ kvout,
                                                const int* __restrict__ pos,
                                                const float* __restrict__ cosT, const float* __restrict__ sinT) {
    __shared__ u16 As[2][64 * BK];
    __shared__ u16 Bs[2][128 * BK];
    const int tid = threadIdx.x;
    const int wid = tid >> 6, lane = tid & 63;
    const int lm = lane & 15, lk = lane >> 4;

    const bool isq = blockIdx.x < 768;
    const int gx = isq ? blockIdx.x : blockIdx.x - 768;
    const int nb = isq ? 24 : 32;
    const int K  = isq ? 1536 : 512;
    const u16* A = isq ? qnA : kvnA;
    const u16* B = isq ? qbB : kvbB;
    const long bn = (long)(gx % nb) * 128;
    const long bm = (long)(gx / nb) * 64;

    f32x4 acc[4][2] = {};

    const int rowS = lane >> 2;
    const int colS = ((lane & 3) ^ ((lane >> 3) & 3)) * 8;
    const int cs = (lm >> 1) & 3;
    const u16* Ag = A + (bm + wid * 16 + rowS) * (long)K + colS;
    const u16* Bg = B + (bn + wid * 32 + rowS) * (long)K + colS;
    const int aoff = wid * 16 * BK;
    const int boff = wid * 32 * BK;

    gload16(Ag, &As[0][aoff]);
    gload16(Bg, &Bs[0][boff]);
    gload16(Bg + 16 * (long)K, &Bs[0][boff + 16 * BK]);
    __syncthreads();

    int cur = 0;
    for (int k0 = 0; k0 < K; k0 += BK) {
        if (k0 + BK < K) {
            gload16(Ag + k0 + BK, &As[cur ^ 1][aoff]);
            gload16(Bg + k0 + BK, &Bs[cur ^ 1][boff]);
            gload16(Bg + 16 * (long)K + k0 + BK, &Bs[cur ^ 1][boff + 16 * BK]);
        }
        short8 af[4], bfr[2];
#pragma unroll
        for (int m = 0; m < 4; ++m)
            af[m] = *(const short8*)&As[cur][(m * 16 + lm) * BK + (lk ^ cs) * 8];
#pragma unroll
        for (int n = 0; n < 2; ++n)
            bfr[n] = *(const short8*)&Bs[cur][(wid * 32 + n * 16 + lm) * BK + (lk ^ cs) * 8];
#pragma unroll
        for (int m = 0; m < 4; ++m)
#pragma unroll
            for (int n = 0; n < 2; ++n)
                acc[m][n] = __builtin_amdgcn_mfma_f32_16x16x32_bf16(af[m], bfr[n], acc[m][n], 0, 0, 0);
        __syncthreads();
        cur ^= 1;
    }

    if (!isq) {
        // kv route: plain row-major bf16 store (N = 4096)
#pragma unroll
        for (int m = 0; m < 4; ++m)
#pragma unroll
            for (int n = 0; n < 2; ++n)
#pragma unroll
                for (int r = 0; r < 4; ++r) {
                    long idx = (bm + m * 16 + lk * 4 + r) * 4096L + bn + wid * 32 + n * 16 + lm;
                    kvout[idx] = f2bf(acc[m][n][r]);
                }
    } else {
        // q route: write Qb[h][row][d] with interleaved RoPE on d in [128,192)
        // q'[2t]   = x[2t]*c - x[2t+1]*s      (even lane of pair)
        // q'[2t+1] = x[2t+1]*c + x[2t]*s      (odd lane; c,s shared: cos[t]==cos[t+32])
#pragma unroll
        for (int n = 0; n < 2; ++n) {
            const int c = (int)bn + wid * 32 + n * 16 + lm;
            const int h = c / 192;
            const int d = c - h * 192;
            const bool pe = (d >= 128);
            const int t = (d - 128) >> 1;
#pragma unroll
            for (int m = 0; m < 4; ++m)
#pragma unroll
                for (int r = 0; r < 4; ++r) {
                    const long row = bm + m * 16 + lk * 4 + r;
                    float own = acc[m][n][r];
                    float par = dpp_xor1(own);
                    float val = own;
                    if (pe) {
                        long p = pos[row];
                        float cc = cosT[p * 64 + t];
                        float ss = sinT[p * 64 + t];
                        val = (d & 1) ? own * cc + par * ss : own * cc - par * ss;
                    }
                    Qb[((long)h * 2048 + row) * 192 + d] = f2bf(val);
                }
        }
    }
}

// ---------------- RMSNorm (f32 in, bf16 out) ----------------
__global__ __launch_bounds__(256) void rmsnorm_bf16(const float* __restrict__ in, const float* __restrict__ w,
                                                    u16* __restrict__ out, int ldin, int ldout, int ncols) {
    const int row = blockIdx.x, tid = threadIdx.x;
    const float* x = in + (long)row * ldin;
    float ss = 0.f;
    for (int c = tid; c < ncols; c += 256) { float v = x[c]; ss = fmaf(v, v, ss); }
#pragma unroll
    for (int off = 32; off > 0; off >>= 1) ss += __shfl_down(ss, off);
    __shared__ float part[4];
    if ((tid & 63) == 0) part[tid >> 6] = ss;
    __syncthreads();
    float tot = part[0] + part[1] + part[2] + part[3];
    float rs = rsqrtf(tot / (float)ncols + 1e-6f);
    for (int c = tid; c < ncols; c += 256) out[(long)row * ldout + c] = f2bf(x[c] * rs * w[c]);
}

// ---------------- k_pe RoPE (interleaved pair layout, matches q-route epilogue) ----------------
__global__ void rope_k(const float* __restrict__ ckv, const int* __restrict__ pos,
                       const float* __restrict__ cosT, const float* __restrict__ sinT,
                       u16* __restrict__ Kb) {
    int idx = blockIdx.x * 256 + threadIdx.x;
    if (idx >= 2048 * 32) return;
    int s = idx >> 5, j = idx & 31;
    long p = pos[s];
    const float* row = ckv + (long)s * 2176 + 2048;
    float x0 = row[2 * j], x1 = row[2 * j + 1];
    float c0 = cosT[p * 64 + j], s0 = sinT[p * 64 + j];   // cos[j]==cos[j+32]
    u16 o0 = f2bf(x0 * c0 - x1 * s0);
    u16 o1 = f2bf(x1 * c0 + x0 * s0);
#pragma unroll
    for (int h = 0; h < 16; ++h) {
        u16* kr = Kb + ((long)h * 2048 + s) * 192 + 128;
        kr[2 * j] = o0; kr[2 * j + 1] = o1;
    }
}

// ---------------- K-nope copy + V transpose (single pass over kv, bf16 in) ----------------
__global__ __launch_bounds__(256) void build_kv2(const u16* __restrict__ kv, u16* __restrict__ Kb,
                                                 u16* __restrict__ Vt) {
    __shared__ u16 Ls[128][72];
    const int h = blockIdx.y, s0 = blockIdx.x * 64;
    const int tid = threadIdx.x;
#pragma unroll
    for (int i = 0; i < 8; ++i) {
        int u = i * 256 + tid;
        int r = u >> 5, c8 = (u & 31) * 8;
        short8 x = *(const short8*)(kv + (long)(s0 + r) * 4096 + h * 256 + c8);
        if (c8 < 128) {
            *(short8*)(Kb + ((long)h * 2048 + s0 + r) * 192 + c8) = x;
        } else {
#pragma unroll
            for (int j = 0; j < 8; ++j) {
                int d = c8 - 128 + j;
                Ls[d][r ^ (((d >> 3) & 7) << 3)] = (u16)x[j];
            }
        }
    }
    __syncthreads();
#pragma unroll
    for (int i = 0; i < 8; ++i) {
        int u = i * 256 + tid;
        int d = u >> 4, s4 = (u & 15) * 4;
        int swz = ((d >> 3) & 7) << 3;
        ushort4_t v;
        v.x = Ls[d][(s4 + 0) ^ swz]; v.y = Ls[d][(s4 + 1) ^ swz];
        v.z = Ls[d][(s4 + 2) ^ swz]; v.w = Ls[d][(s4 + 3) ^ swz];
        *(ushort4_t*)(Vt + ((long)h * 128 + d) * 2048 + s0 + s4) = v;
    }
}

// ---------------- causal flash attention (unchanged) ----------------
__global__ __launch_bounds__(512) void attn_fwd(const u16* __restrict__ Qb, const u16* __restrict__ Kb,
                                                const u16* __restrict__ Vt, u16* __restrict__ Ao) {
    __shared__ __align__(16) char smem[92672];

    const int b = blockIdx.x;
    const int h = (b & 7) * 2 + ((b >> 3) & 1);
    const int pi = b >> 4;
    const int tid = threadIdx.x;
    const int wid = tid >> 6, lane = tid & 63;
    const int lm = lane & 15, lk = lane >> 4;
    const int s = wid >> 2, wp = wid & 3;
    const int t256 = tid & 255;

    u16* Ks0 = (u16*)smem + s * 12288;
    u16* Vs0 = (u16*)(smem + 49152) + s * 8192;
    u16* PsW = (u16*)(smem + 81920) + wid * 640;
    float* ML = (float*)(smem + 92160);
    float* Ob = (float*)smem;

    const u16* Kh = Kb + (long)h * 2048 * 192;
    const u16* Vh = Vt + (long)h * 128 * 2048;

    short8 bones = {};
    if (lm == 0) {
#pragma unroll
        for (int j = 0; j < 8; ++j) bones[j] = (short)0x3F80;
    }
    const float C2 = 0.104117548f;   // 192^-0.5 * log2(e)

    for (int half = 0; half < 2; ++half) {
        const int qi = half ? (31 - pi) : pi;
        const int q0 = qi * 64;
        const int nt = 2 * qi + 2;
        const int niter = qi + 1;

        short8 qf[6];
        const u16* qbase = Qb + ((long)h * 2048 + q0 + wp * 16 + lm) * 192;
#pragma unroll
        for (int kf = 0; kf < 6; ++kf) qf[kf] = *(const short8*)(qbase + kf * 32 + lk * 8);

        f32x4 o[8] = {};
        f32x4 o9 = {};
        float mrow[4] = {-1e30f, -1e30f, -1e30f, -1e30f};

        short8 kreg[3], vreg[2];
        {
            const long k0 = s * 32;
#pragma unroll
            for (int i = 0; i < 3; ++i) {
                int idx = i * 256 + t256; int r = idx / 24, c = (idx % 24) * 8;
                kreg[i] = *(const short8*)(Kh + (k0 + r) * 192 + c);
            }
#pragma unroll
            for (int i = 0; i < 2; ++i) {
                int idx = i * 256 + t256; int dv = idx >> 2, kvb = idx & 3;
                vreg[i] = *(const short8*)(Vh + (long)dv * 2048 + k0 + kvb * 8);
            }
#pragma unroll
            for (int i = 0; i < 3; ++i) {
                int idx = i * 256 + t256; int r = idx / 24, c8 = idx % 24;
                *(short8*)&Ks0[r * 192 + ((c8 ^ (r & 7)) << 3)] = kreg[i];
            }
#pragma unroll
            for (int i = 0; i < 2; ++i) {
                int idx = i * 256 + t256; int dv = idx >> 2, kvb = idx & 3;
                *(short8*)&Vs0[kvb * 1024 + ((dv * 8) ^ (kvb * 16))] = vreg[i];
            }
        }
        __syncthreads();

        int cur = 0;
        for (int it = 0; it < niter; ++it) {
            const int ts = 2 * it + s;
            const int k0 = ts * 32;
            const bool more = (it + 1 < niter);

            if (more) {
                const long k0n = (long)(ts + 2) * 32;
#pragma unroll
                for (int i = 0; i < 3; ++i) {
                    int idx = i * 256 + t256; int r = idx / 24, c = (idx % 24) * 8;
                    kreg[i] = *(const short8*)(Kh + (k0n + r) * 192 + c);
                }
#pragma unroll
                for (int i = 0; i < 2; ++i) {
                    int idx = i * 256 + t256; int dv = idx >> 2, kvb = idx & 3;
                    vreg[i] = *(const short8*)(Vh + (long)dv * 2048 + k0n + kvb * 8);
                }
            }

            const u16* KsC = Ks0 + cur * 6144;
            const u16* VsC = Vs0 + cur * 4096;

            f32x4 sfr[2] = {};
#pragma unroll
            for (int n = 0; n < 2; ++n)
#pragma unroll
                for (int kf = 0; kf < 6; ++kf) {
                    short8 kb = *(const short8*)&KsC[(n * 16 + lm) * 192 + (((kf * 4 + lk) ^ (lm & 7)) << 3)];
                    sfr[n] = __builtin_amdgcn_mfma_f32_16x16x32_bf16(qf[kf], kb, sfr[n], 0, 0, 0);
                }

            float sv[2][4];
            const bool bt = (ts >= nt - 2);
#pragma unroll
            for (int n = 0; n < 2; ++n)
#pragma unroll
                for (int r = 0; r < 4; ++r) {
                    float val = sfr[n][r] * C2;
                    if (bt && (k0 + n * 16 + lm > q0 + wp * 16 + lk * 4 + r)) val = -1e30f;
                    sv[n][r] = val;
                }

            float pmax[4];
#pragma unroll
            for (int r = 0; r < 4; ++r)
                pmax[r] = rmax16(fmaxf(sv[0][r], sv[1][r]));
            bool need = (pmax[0] > mrow[0] + 8.f) || (pmax[1] > mrow[1] + 8.f) ||
                        (pmax[2] > mrow[2] + 8.f) || (pmax[3] > mrow[3] + 8.f);
            if (__any(need)) {
#pragma unroll
                for (int r = 0; r < 4; ++r) {
                    float mnew = fmaxf(mrow[r], pmax[r]);
                    float alpha = fexp2(mrow[r] - mnew);
                    mrow[r] = mnew;
#pragma unroll
                    for (int d = 0; d < 8; ++d) o[d][r] *= alpha;
                    o9[r] *= alpha;
                }
            }
#pragma unroll
            for (int n = 0; n < 2; ++n) {
                float p0 = fexp2(sv[n][0] - mrow[0]);
                float p1 = fexp2(sv[n][1] - mrow[1]);
                float p2 = fexp2(sv[n][2] - mrow[2]);
                float p3 = fexp2(sv[n][3] - mrow[3]);
                unsigned pk01 = cvtpk_bf16(p0, p1);
                unsigned pk23 = cvtpk_bf16(p2, p3);
                int rb = (lk * 4) * 40 + n * 16 + lm;
                PsW[rb]       = (u16)pk01;
                PsW[rb + 40]  = (u16)(pk01 >> 16);
                PsW[rb + 80]  = (u16)pk23;
                PsW[rb + 120] = (u16)(pk23 >> 16);
            }

            short8 pf = *(const short8*)&PsW[lm * 40 + lk * 8];
#pragma unroll
            for (int d = 0; d < 8; ++d) {
                short8 vf = *(const short8*)&VsC[lk * 1024 + (((d * 16 + lm) * 8) ^ (lk * 16))];
                o[d] = __builtin_amdgcn_mfma_f32_16x16x32_bf16(pf, vf, o[d], 0, 0, 0);
            }
            o9 = __builtin_amdgcn_mfma_f32_16x16x32_bf16(pf, bones, o9, 0, 0, 0);

            if (more) {
                u16* KsN = Ks0 + (cur ^ 1) * 6144;
                u16* VsN = Vs0 + (cur ^ 1) * 4096;
#pragma unroll
                for (int i = 0; i < 3; ++i) {
                    int idx = i * 256 + t256; int r = idx / 24, c8 = idx % 24;
                    *(short8*)&KsN[r * 192 + ((c8 ^ (r & 7)) << 3)] = kreg[i];
                }
#pragma unroll
                for (int i = 0; i < 2; ++i) {
                    int idx = i * 256 + t256; int dv = idx >> 2, kvb = idx & 3;
                    *(short8*)&VsN[kvb * 1024 + ((dv * 8) ^ (kvb * 16))] = vreg[i];
                }
            }
            __syncthreads();
            cur ^= 1;
        }

        if (s == 1) {
#pragma unroll
            for (int d = 0; d < 8; ++d)
#pragma unroll
                for (int r = 0; r < 4; ++r)
                    Ob[(wp * 16 + lk * 4 + r) * 128 + d * 16 + lm] = o[d][r];
            if (lm == 0) {
#pragma unroll
                for (int r = 0; r < 4; ++r) {
                    int row = wp * 16 + lk * 4 + r;
                    ML[row * 2 + 0] = mrow[r];
                    ML[row * 2 + 1] = o9[r];
                }
            }
        }
        __syncthreads();
        if (s == 0) {
            float e0[4], e1[4], invl[4];
#pragma unroll
            for (int r = 0; r < 4; ++r) {
                int row = wp * 16 + lk * 4 + r;
                float m1 = ML[row * 2 + 0];
                float l1 = ML[row * 2 + 1];
                float l0 = __shfl(o9[r], lane & 48);
                float M = fmaxf(mrow[r], m1);
                e0[r] = fexp2(mrow[r] - M);
                e1[r] = fexp2(m1 - M);
                invl[r] = 1.f / (l0 * e0[r] + l1 * e1[r]);
            }
#pragma unroll
            for (int d = 0; d < 8; ++d)
#pragma unroll
                for (int r = 0; r < 4; ++r) {
                    int row = wp * 16 + lk * 4 + r;
                    float val = (o[d][r] * e0[r] +
                                 Ob[row * 128 + d * 16 + lm] * e1[r]) * invl[r];
                    Ao[((long)q0 + row) * 2048 + h * 128 + d * 16 + lm] = f2bf(val);
                }
        }
        __syncthreads();
    }
}

// ---------------- host launch ----------------
extern "C" void kernel_launch(void* const* d_in, const int* in_sizes, int n_in,
                              void* d_out, int out_size, void* d_ws, size_t ws_size,
                              hipStream_t stream) {
    (void)in_sizes; (void)n_in; (void)out_size; (void)ws_size;
    const float* hidden  = (const float*)d_in[0];
    const float* q_a_w   = (const float*)d_in[1];
    const float* q_a_ln  = (const float*)d_in[2];
    const float* q_b_w   = (const float*)d_in[3];
    const float* kv_a_w  = (const float*)d_in[4];
    const float* kv_a_ln = (const float*)d_in[5];
    const float* kv_b_w  = (const float*)d_in[6];
    const float* o_w     = (const float*)d_in[7];
    const float* cosT    = (const float*)d_in[8];
    const float* sinT    = (const float*)d_in[9];
    const int*   pos     = (const int*)d_in[11];

    char* ws = (char*)d_ws;
    // persistent zone
    u16* o_w_bf   = (u16*)(ws + 0);          // 2048x2048
    u16* qb_w_bf  = (u16*)(ws + 8388608);    // 3072x1536
    u16* kvb_w_bf = (u16*)(ws + 17825792);   // 4096x512
    u16* qn_bf    = (u16*)(ws + 22020096);   // 2048x1536
    u16* kvn_bf   = (u16*)(ws + 28311552);   // 2048x512
    u16* Qb       = (u16*)(ws + 30408704);   // 16x2048x192
    u16* Kb       = (u16*)(ws + 42991616);   // 16x2048x192
    u16* Vt       = (u16*)(ws + 55574528);   // 16x128x2048
    u16* aout_bf  = (u16*)(ws + 63963136);   // 2048x2048, ends 72351744
    // transient zone
    u16*   hid_bf    = (u16*)(ws + 72351744);   // 2048x2048 bf16
    u16*   qkva_w_bf = (u16*)(ws + 80740352);   // 2176x2048 bf16
    float* qkva_f    = (float*)(ws + 89653248); // 2048x2176 f32, ends 107479040
    u16*   kv_f_bf   = (u16*)(ws + 107479040);  // 2048x4096 bf16, ends 124256256

    // converts
    conv_multi<<<17920, 256, 0, stream>>>(
        hidden, hid_bf,    1048576L,
        q_a_w,  qkva_w_bf, 1835008L,
        q_b_w,  qb_w_bf,   3014656L,
        kv_b_w, kvb_w_bf,  3538944L,
        o_w,    o_w_bf,    4587520L);
    conv_pad<<<(640L*2048/4 + 255)/256, 256, 0, stream>>>(kv_a_w, qkva_w_bf + 1536L*2048, 576, 640L*2048/4, 512);

    // fused down-projection: [2048,2048] x [2176,2048]^T -> [2048,2176] f32 (544 blocks)
    gemm64_db<float><<<dim3(17, 32), 256, 0, stream>>>(hid_bf, qkva_w_bf, qkva_f, 2048, 2176, 2048);

    // norms + k_pe rope (interleaved layout)
    rmsnorm_bf16<<<2048, 256, 0, stream>>>(qkva_f, q_a_ln, qn_bf, 2176, 1536, 1536);
    rmsnorm_bf16<<<2048, 256, 0, stream>>>(qkva_f + 1536, kv_a_ln, kvn_bf, 2176, 512, 512);
    rope_k<<<(2048*32)/256, 256, 0, stream>>>(qkva_f, pos, cosT, sinT, Kb);

    // fused up-projections: q_b (-> Qb w/ RoPE) + kv_b (-> kv_f) in one 1792-block launch
    gemm_qkv<<<1792, 256, 0, stream>>>(qn_bf, qb_w_bf, kvn_bf, kvb_w_bf, Qb, kv_f_bf, pos, cosT, sinT);

    // K-nope + V^T assembly
    build_kv2<<<dim3(32, 16), 256, 0, stream>>>(kv_f_bf, Kb, Vt);

    // attention (256 blocks x 512 threads)
    attn_fwd<<<256, 512, 0, stream>>>(Qb, Kb, Vt, aout_bf);

    // output projection -> d_out (f32), 512 blocks
    gemm64_db<float><<<dim3(16, 32), 256, 0, stream>>>(aout_bf, o_w_bf, (float*)d_out, 2048, 2048, 2048);
}

// Round 13
// 223.229 us; speedup vs baseline: 1.1346x; 1.0565x over previous
//
#include <hip/hip_runtime.h>
#include <stdint.h>

typedef unsigned short u16;
typedef __attribute__((ext_vector_type(8))) short short8;
typedef __attribute__((ext_vector_type(4))) float f32x4;
typedef __attribute__((ext_vector_type(4))) unsigned short ushort4_t;
typedef __attribute__((ext_vector_type(4))) float float4_t;

#define DEV_INLINE __device__ __forceinline__

DEV_INLINE u16 f2bf(float f) {
    union { float f; unsigned u; } x; x.f = f;
    unsigned u = x.u;
    unsigned r = (u + 0x7FFFu + ((u >> 16) & 1u)) >> 16;
    return (u16)r;
}

DEV_INLINE float bf2f(u16 b) {
    union { unsigned u; float f; } x; x.u = ((unsigned)b) << 16;
    return x.f;
}

DEV_INLINE float fexp2(float x) {
    float r;
    asm("v_exp_f32 %0, %1" : "=v"(r) : "v"(x));
    return r;
}

DEV_INLINE unsigned cvtpk_bf16(float lo, float hi) {
    unsigned r;
    asm("v_cvt_pk_bf16_f32 %0, %1, %2" : "=v"(r) : "v"(lo), "v"(hi));
    return r;
}

template <int CTRL>
DEV_INLINE float dppmaxf(float x) {
    union { float f; int i; } u; u.f = x;
    int y = __builtin_amdgcn_update_dpp(u.i, u.i, CTRL, 0xf, 0xf, true);
    union { int i; float f; } v; v.i = y;
    return fmaxf(x, v.f);
}

// exchange with neighbor lane (lane ^ 1)
DEV_INLINE float dpp_xor1(float x) {
    union { float f; int i; } u; u.f = x;
    int y = __builtin_amdgcn_update_dpp(u.i, u.i, 0xB1, 0xf, 0xf, true);
    union { int i; float f; } v; v.i = y;
    return v.f;
}

// max across each 16-lane group, no LDS
DEV_INLINE float rmax16(float x) {
    x = dppmaxf<0xB1>(x);    // quad_perm xor 1
    x = dppmaxf<0x4E>(x);    // quad_perm xor 2
    x = dppmaxf<0x141>(x);   // row_half_mirror (xor 7)
    x = dppmaxf<0x140>(x);   // row_mirror (xor 15)
    return x;
}

// ---------------- fused convert: 5 plain segments + 1 padded segment ----------------
__global__ void conv_all(const float* __restrict__ s0, u16* __restrict__ d0, long e0,
                         const float* __restrict__ s1, u16* __restrict__ d1, long e1,
                         const float* __restrict__ s2, u16* __restrict__ d2, long e2,
                         const float* __restrict__ s3, u16* __restrict__ d3, long e3,
                         const float* __restrict__ s4, u16* __restrict__ d4, long e4,
                         const float* __restrict__ s5, u16* __restrict__ d5, long e5,
                         int rows_valid, int cols4) {
    long i = (long)blockIdx.x * 256 + threadIdx.x;
    if (i >= e5) return;
    if (i >= e4) {
        // padded segment (kv_a_w: zero rows >= rows_valid)
        long j = i - e4;
        long row = j / cols4;
        ushort4_t o; o.x = 0; o.y = 0; o.z = 0; o.w = 0;
        if (row < rows_valid) {
            float4_t v = ((const float4_t*)s5)[j];
            o.x = f2bf(v.x); o.y = f2bf(v.y); o.z = f2bf(v.z); o.w = f2bf(v.w);
        }
        ((ushort4_t*)d5)[j] = o;
        return;
    }
    const float* s; u16* d; long base;
    if      (i < e0) { s = s0; d = d0; base = 0; }
    else if (i < e1) { s = s1; d = d1; base = e0; }
    else if (i < e2) { s = s2; d = d2; base = e1; }
    else if (i < e3) { s = s3; d = d3; base = e2; }
    else             { s = s4; d = d4; base = e3; }
    long j = i - base;
    float4_t v = ((const float4_t*)s)[j];
    ushort4_t o;
    o.x = f2bf(v.x); o.y = f2bf(v.y); o.z = f2bf(v.z); o.w = f2bf(v.w);
    ((ushort4_t*)d)[j] = o;
}

#define BK 32

DEV_INLINE void gload16(const u16* g, u16* l) {
    __builtin_amdgcn_global_load_lds((const __attribute__((address_space(1))) unsigned int*)g,
                                     (__attribute__((address_space(3))) unsigned int*)l,
                                     16, 0, 0);
}

// ---------------- GEMM 64x128 double-buffered ----------------
template <typename OT>
__global__ __launch_bounds__(256) void gemm64_db(const u16* __restrict__ A, const u16* __restrict__ B,
                                                 OT* __restrict__ C, int M, int N, int K) {
    __shared__ u16 As[2][64 * BK];
    __shared__ u16 Bs[2][128 * BK];
    const int tid = threadIdx.x;
    const int wid = tid >> 6, lane = tid & 63;
    const int lm = lane & 15, lk = lane >> 4;
    const long bm = (long)blockIdx.y * 64, bn = (long)blockIdx.x * 128;

    f32x4 acc[4][2] = {};

    const int rowS = lane >> 2;
    const int colS = ((lane & 3) ^ ((lane >> 3) & 3)) * 8;
    const int cs = (lm >> 1) & 3;
    const u16* Ag = A + (bm + wid * 16 + rowS) * (long)K + colS;
    const u16* Bg = B + (bn + wid * 32 + rowS) * (long)K + colS;
    const int aoff = wid * 16 * BK;
    const int boff = wid * 32 * BK;

    gload16(Ag, &As[0][aoff]);
    gload16(Bg, &Bs[0][boff]);
    gload16(Bg + 16 * (long)K, &Bs[0][boff + 16 * BK]);
    __syncthreads();

    int cur = 0;
    for (int k0 = 0; k0 < K; k0 += BK) {
        if (k0 + BK < K) {
            gload16(Ag + k0 + BK, &As[cur ^ 1][aoff]);
            gload16(Bg + k0 + BK, &Bs[cur ^ 1][boff]);
            gload16(Bg + 16 * (long)K + k0 + BK, &Bs[cur ^ 1][boff + 16 * BK]);
        }
        short8 af[4], bfr[2];
#pragma unroll
        for (int m = 0; m < 4; ++m)
            af[m] = *(const short8*)&As[cur][(m * 16 + lm) * BK + (lk ^ cs) * 8];
#pragma unroll
        for (int n = 0; n < 2; ++n)
            bfr[n] = *(const short8*)&Bs[cur][(wid * 32 + n * 16 + lm) * BK + (lk ^ cs) * 8];
#pragma unroll
        for (int m = 0; m < 4; ++m)
#pragma unroll
            for (int n = 0; n < 2; ++n)
                acc[m][n] = __builtin_amdgcn_mfma_f32_16x16x32_bf16(af[m], bfr[n], acc[m][n], 0, 0, 0);
        __syncthreads();
        cur ^= 1;
    }

#pragma unroll
    for (int m = 0; m < 4; ++m)
#pragma unroll
        for (int n = 0; n < 2; ++n)
#pragma unroll
            for (int r = 0; r < 4; ++r) {
                long idx = (bm + m * 16 + lk * 4 + r) * (long)N + bn + wid * 32 + n * 16 + lm;
                if constexpr (sizeof(OT) == 4) C[idx] = acc[m][n][r];
                else                           C[idx] = f2bf(acc[m][n][r]);
            }
}

// ---------------- dual GEMM: q_b (Qb direct + RoPE) and kv_b (Kb-nope + Vt direct) ----------------
// blocks [0,768): q route:  [2048x1536] x [3072x1536]^T -> Qb with interleaved RoPE
// blocks [768,1792): kv route: [2048x512] x [4096x512]^T
//   even kv block (gx&1==0): K-half  -> Kb[h][s][0:128]
//   odd  kv block (gx&1==1): V-half  -> Vt[h][d][s] (LDS transpose)
__global__ __launch_bounds__(256) void gemm_qkv(const u16* __restrict__ qnA, const u16* __restrict__ qbB,
                                                const u16* __restrict__ kvnA, const u16* __restrict__ kvbB,
                                                u16* __restrict__ Qb, u16* __restrict__ Kb, u16* __restrict__ Vt,
                                                const int* __restrict__ pos,
                                                const float* __restrict__ cosT, const float* __restrict__ sinT) {
    __shared__ u16 SMEM[12288];           // As[2][2048] ++ Bs[2][4096]; reused as Ls[128][72]
    u16* As = SMEM;
    u16* Bs = SMEM + 4096;
    const int tid = threadIdx.x;
    const int wid = tid >> 6, lane = tid & 63;
    const int lm = lane & 15, lk = lane >> 4;

    const bool isq = blockIdx.x < 768;
    const int gx = isq ? blockIdx.x : blockIdx.x - 768;
    const int nb = isq ? 24 : 32;
    const int K  = isq ? 1536 : 512;
    const u16* A = isq ? qnA : kvnA;
    const u16* B = isq ? qbB : kvbB;
    const long bn = (long)(gx % nb) * 128;
    const long bm = (long)(gx / nb) * 64;

    f32x4 acc[4][2] = {};

    const int rowS = lane >> 2;
    const int colS = ((lane & 3) ^ ((lane >> 3) & 3)) * 8;
    const int cs = (lm >> 1) & 3;
    const u16* Ag = A + (bm + wid * 16 + rowS) * (long)K + colS;
    const u16* Bg = B + (bn + wid * 32 + rowS) * (long)K + colS;
    const int aoff = wid * 16 * BK;
    const int boff = wid * 32 * BK;

    gload16(Ag, &As[aoff]);
    gload16(Bg, &Bs[boff]);
    gload16(Bg + 16 * (long)K, &Bs[boff + 16 * BK]);
    __syncthreads();

    int cur = 0;
    for (int k0 = 0; k0 < K; k0 += BK) {
        if (k0 + BK < K) {
            gload16(Ag + k0 + BK, &As[(cur ^ 1) * 2048 + aoff]);
            gload16(Bg + k0 + BK, &Bs[(cur ^ 1) * 4096 + boff]);
            gload16(Bg + 16 * (long)K + k0 + BK, &Bs[(cur ^ 1) * 4096 + boff + 16 * BK]);
        }
        short8 af[4], bfr[2];
#pragma unroll
        for (int m = 0; m < 4; ++m)
            af[m] = *(const short8*)&As[cur * 2048 + (m * 16 + lm) * BK + (lk ^ cs) * 8];
#pragma unroll
        for (int n = 0; n < 2; ++n)
            bfr[n] = *(const short8*)&Bs[cur * 4096 + (wid * 32 + n * 16 + lm) * BK + (lk ^ cs) * 8];
#pragma unroll
        for (int m = 0; m < 4; ++m)
#pragma unroll
            for (int n = 0; n < 2; ++n)
                acc[m][n] = __builtin_amdgcn_mfma_f32_16x16x32_bf16(af[m], bfr[n], acc[m][n], 0, 0, 0);
        __syncthreads();
        cur ^= 1;
    }

    if (isq) {
        // q route: write Qb[h][row][d] with interleaved RoPE on d in [128,192)
#pragma unroll
        for (int n = 0; n < 2; ++n) {
            const int c = (int)bn + wid * 32 + n * 16 + lm;
            const int h = c / 192;
            const int d = c - h * 192;
            const bool pe = (d >= 128);
            const int t = (d - 128) >> 1;
#pragma unroll
            for (int m = 0; m < 4; ++m)
#pragma unroll
                for (int r = 0; r < 4; ++r) {
                    const long row = bm + m * 16 + lk * 4 + r;
                    float own = acc[m][n][r];
                    float par = dpp_xor1(own);
                    float val = own;
                    if (pe) {
                        long p = pos[row];
                        float cc = cosT[p * 64 + t];
                        float ss = sinT[p * 64 + t];
                        val = (d & 1) ? own * cc + par * ss : own * cc - par * ss;
                    }
                    Qb[((long)h * 2048 + row) * 192 + d] = f2bf(val);
                }
        }
    } else {
        const int hh = (gx & 31) >> 1;
        const bool isV = (gx & 1) != 0;
        if (!isV) {
            // K-half: straight rows into Kb nope region
#pragma unroll
            for (int m = 0; m < 4; ++m)
#pragma unroll
                for (int n = 0; n < 2; ++n)
#pragma unroll
                    for (int r = 0; r < 4; ++r)
                        Kb[((long)hh * 2048 + bm + m * 16 + lk * 4 + r) * 192 + wid * 32 + n * 16 + lm]
                            = f2bf(acc[m][n][r]);
        } else {
            // V-half: transpose 64 rows x 128 d via LDS (swizzled), store Vt[h][d][s]
            __syncthreads();                 // done with As/Bs
            u16* Ls = SMEM;                  // [128][72]
#pragma unroll
            for (int n = 0; n < 2; ++n) {
                int d = wid * 32 + n * 16 + lm;
                int swz = ((d >> 3) & 7) << 3;
#pragma unroll
                for (int m = 0; m < 4; ++m)
#pragma unroll
                    for (int r = 0; r < 4; ++r) {
                        int row = m * 16 + lk * 4 + r;
                        Ls[d * 72 + (row ^ swz)] = f2bf(acc[m][n][r]);
                    }
            }
            __syncthreads();
#pragma unroll
            for (int i = 0; i < 8; ++i) {
                int u = i * 256 + tid;
                int d = u >> 4, s4 = (u & 15) * 4;
                int swz = ((d >> 3) & 7) << 3;
                ushort4_t v;
                v.x = Ls[d * 72 + ((s4 + 0) ^ swz)]; v.y = Ls[d * 72 + ((s4 + 1) ^ swz)];
                v.z = Ls[d * 72 + ((s4 + 2) ^ swz)]; v.w = Ls[d * 72 + ((s4 + 3) ^ swz)];
                *(ushort4_t*)(Vt + ((long)hh * 128 + d) * 2048 + bm + s4) = v;
            }
        }
    }
}

// ---------------- fused rmsnorm (q + kv) and k_pe RoPE in one launch ----------------
// blocks [0,2048): q rmsnorm row; [2048,4096): kv rmsnorm row; [4096,4352): k_pe rope
__global__ __launch_bounds__(256) void norm_rope(const float* __restrict__ qkva,
                                                 const float* __restrict__ q_ln,
                                                 const float* __restrict__ kv_ln,
                                                 u16* __restrict__ qn, u16* __restrict__ kvn,
                                                 const int* __restrict__ pos,
                                                 const float* __restrict__ cosT,
                                                 const float* __restrict__ sinT,
                                                 u16* __restrict__ Kb) {
    const int b = blockIdx.x, tid = threadIdx.x;
    if (b < 4096) {
        const bool isq = b < 2048;
        const int row = isq ? b : b - 2048;
        const int ncols = isq ? 1536 : 512;
        const float* x = qkva + (long)row * 2176 + (isq ? 0 : 1536);
        const float* w = isq ? q_ln : kv_ln;
        u16* out = isq ? (qn + (long)row * 1536) : (kvn + (long)row * 512);
        float ss = 0.f;
        for (int c = tid; c < ncols; c += 256) { float v = x[c]; ss = fmaf(v, v, ss); }
#pragma unroll
        for (int off = 32; off > 0; off >>= 1) ss += __shfl_down(ss, off);
        __shared__ float part[4];
        if ((tid & 63) == 0) part[tid >> 6] = ss;
        __syncthreads();
        float tot = part[0] + part[1] + part[2] + part[3];
        float rs = rsqrtf(tot / (float)ncols + 1e-6f);
        for (int c = tid; c < ncols; c += 256) out[c] = f2bf(x[c] * rs * w[c]);
    } else {
        int idx = (b - 4096) * 256 + tid;    // 2048*32 work items
        int s = idx >> 5, j = idx & 31;
        long p = pos[s];
        const float* row = qkva + (long)s * 2176 + 2048;
        float x0 = row[2 * j], x1 = row[2 * j + 1];
        float c0 = cosT[p * 64 + j], s0 = sinT[p * 64 + j];   // cos[j]==cos[j+32]
        u16 o0 = f2bf(x0 * c0 - x1 * s0);
        u16 o1 = f2bf(x1 * c0 + x0 * s0);
#pragma unroll
        for (int h = 0; h < 16; ++h) {
            u16* kr = Kb + ((long)h * 2048 + s) * 192 + 128;
            kr[2 * j] = o0; kr[2 * j + 1] = o1;
        }
    }
}

// ---------------- causal flash attention (unchanged) ----------------
__global__ __launch_bounds__(512) void attn_fwd(const u16* __restrict__ Qb, const u16* __restrict__ Kb,
                                                const u16* __restrict__ Vt, u16* __restrict__ Ao) {
    __shared__ __align__(16) char smem[92672];

    const int b = blockIdx.x;
    const int h = (b & 7) * 2 + ((b >> 3) & 1);
    const int pi = b >> 4;
    const int tid = threadIdx.x;
    const int wid = tid >> 6, lane = tid & 63;
    const int lm = lane & 15, lk = lane >> 4;
    const int s = wid >> 2, wp = wid & 3;
    const int t256 = tid & 255;

    u16* Ks0 = (u16*)smem + s * 12288;
    u16* Vs0 = (u16*)(smem + 49152) + s * 8192;
    u16* PsW = (u16*)(smem + 81920) + wid * 640;
    float* ML = (float*)(smem + 92160);
    float* Ob = (float*)smem;

    const u16* Kh = Kb + (long)h * 2048 * 192;
    const u16* Vh = Vt + (long)h * 128 * 2048;

    short8 bones = {};
    if (lm == 0) {
#pragma unroll
        for (int j = 0; j < 8; ++j) bones[j] = (short)0x3F80;
    }
    const float C2 = 0.104117548f;   // 192^-0.5 * log2(e)

    for (int half = 0; half < 2; ++half) {
        const int qi = half ? (31 - pi) : pi;
        const int q0 = qi * 64;
        const int nt = 2 * qi + 2;
        const int niter = qi + 1;

        short8 qf[6];
        const u16* qbase = Qb + ((long)h * 2048 + q0 + wp * 16 + lm) * 192;
#pragma unroll
        for (int kf = 0; kf < 6; ++kf) qf[kf] = *(const short8*)(qbase + kf * 32 + lk * 8);

        f32x4 o[8] = {};
        f32x4 o9 = {};
        float mrow[4] = {-1e30f, -1e30f, -1e30f, -1e30f};

        short8 kreg[3], vreg[2];
        {
            const long k0 = s * 32;
#pragma unroll
            for (int i = 0; i < 3; ++i) {
                int idx = i * 256 + t256; int r = idx / 24, c = (idx % 24) * 8;
                kreg[i] = *(const short8*)(Kh + (k0 + r) * 192 + c);
            }
#pragma unroll
            for (int i = 0; i < 2; ++i) {
                int idx = i * 256 + t256; int dv = idx >> 2, kvb = idx & 3;
                vreg[i] = *(const short8*)(Vh + (long)dv * 2048 + k0 + kvb * 8);
            }
#pragma unroll
            for (int i = 0; i < 3; ++i) {
                int idx = i * 256 + t256; int r = idx / 24, c8 = idx % 24;
                *(short8*)&Ks0[r * 192 + ((c8 ^ (r & 7)) << 3)] = kreg[i];
            }
#pragma unroll
            for (int i = 0; i < 2; ++i) {
                int idx = i * 256 + t256; int dv = idx >> 2, kvb = idx & 3;
                *(short8*)&Vs0[kvb * 1024 + ((dv * 8) ^ (kvb * 16))] = vreg[i];
            }
        }
        __syncthreads();

        int cur = 0;
        for (int it = 0; it < niter; ++it) {
            const int ts = 2 * it + s;
            const int k0 = ts * 32;
            const bool more = (it + 1 < niter);

            if (more) {
                const long k0n = (long)(ts + 2) * 32;
#pragma unroll
                for (int i = 0; i < 3; ++i) {
                    int idx = i * 256 + t256; int r = idx / 24, c = (idx % 24) * 8;
                    kreg[i] = *(const short8*)(Kh + (k0n + r) * 192 + c);
                }
#pragma unroll
                for (int i = 0; i < 2; ++i) {
                    int idx = i * 256 + t256; int dv = idx >> 2, kvb = idx & 3;
                    vreg[i] = *(const short8*)(Vh + (long)dv * 2048 + k0n + kvb * 8);
                }
            }

            const u16* KsC = Ks0 + cur * 6144;
            const u16* VsC = Vs0 + cur * 4096;

            f32x4 sfr[2] = {};
#pragma unroll
            for (int n = 0; n < 2; ++n)
#pragma unroll
                for (int kf = 0; kf < 6; ++kf) {
                    short8 kb = *(const short8*)&KsC[(n * 16 + lm) * 192 + (((kf * 4 + lk) ^ (lm & 7)) << 3)];
                    sfr[n] = __builtin_amdgcn_mfma_f32_16x16x32_bf16(qf[kf], kb, sfr[n], 0, 0, 0);
                }

            float sv[2][4];
            const bool bt = (ts >= nt - 2);
#pragma unroll
            for (int n = 0; n < 2; ++n)
#pragma unroll
                for (int r = 0; r < 4; ++r) {
                    float val = sfr[n][r] * C2;
                    if (bt && (k0 + n * 16 + lm > q0 + wp * 16 + lk * 4 + r)) val = -1e30f;
                    sv[n][r] = val;
                }

            float pmax[4];
#pragma unroll
            for (int r = 0; r < 4; ++r)
                pmax[r] = rmax16(fmaxf(sv[0][r], sv[1][r]));
            bool need = (pmax[0] > mrow[0] + 8.f) || (pmax[1] > mrow[1] + 8.f) ||
                        (pmax[2] > mrow[2] + 8.f) || (pmax[3] > mrow[3] + 8.f);
            if (__any(need)) {
#pragma unroll
                for (int r = 0; r < 4; ++r) {
                    float mnew = fmaxf(mrow[r], pmax[r]);
                    float alpha = fexp2(mrow[r] - mnew);
                    mrow[r] = mnew;
#pragma unroll
                    for (int d = 0; d < 8; ++d) o[d][r] *= alpha;
                    o9[r] *= alpha;
                }
            }
#pragma unroll
            for (int n = 0; n < 2; ++n) {
                float p0 = fexp2(sv[n][0] - mrow[0]);
                float p1 = fexp2(sv[n][1] - mrow[1]);
                float p2 = fexp2(sv[n][2] - mrow[2]);
                float p3 = fexp2(sv[n][3] - mrow[3]);
                unsigned pk01 = cvtpk_bf16(p0, p1);
                unsigned pk23 = cvtpk_bf16(p2, p3);
                int rb = (lk * 4) * 40 + n * 16 + lm;
                PsW[rb]       = (u16)pk01;
                PsW[rb + 40]  = (u16)(pk01 >> 16);
                PsW[rb + 80]  = (u16)pk23;
                PsW[rb + 120] = (u16)(pk23 >> 16);
            }

            short8 pf = *(const short8*)&PsW[lm * 40 + lk * 8];
#pragma unroll
            for (int d = 0; d < 8; ++d) {
                short8 vf = *(const short8*)&VsC[lk * 1024 + (((d * 16 + lm) * 8) ^ (lk * 16))];
                o[d] = __builtin_amdgcn_mfma_f32_16x16x32_bf16(pf, vf, o[d], 0, 0, 0);
            }
            o9 = __builtin_amdgcn_mfma_f32_16x16x32_bf16(pf, bones, o9, 0, 0, 0);

            if (more) {
                u16* KsN = Ks0 + (cur ^ 1) * 6144;
                u16* VsN = Vs0 + (cur ^ 1) * 4096;
#pragma unroll
                for (int i = 0; i < 3; ++i) {
                    int idx = i * 256 + t256; int r = idx / 24, c8 = idx % 24;
                    *(short8*)&KsN[r * 192 + ((c8 ^ (r & 7)) << 3)] = kreg[i];
                }
#pragma unroll
                for (int i = 0; i < 2; ++i) {
                    int idx = i * 256 + t256; int dv = idx >> 2, kvb = idx & 3;
                    *(short8*)&VsN[kvb * 1024 + ((dv * 8) ^ (kvb * 16))] = vreg[i];
                }
            }
            __syncthreads();
            cur ^= 1;
        }

        if (s == 1) {
#pragma unroll
            for (int d = 0; d < 8; ++d)
#pragma unroll
                for (int r = 0; r < 4; ++r)
                    Ob[(wp * 16 + lk * 4 + r) * 128 + d * 16 + lm] = o[d][r];
            if (lm == 0) {
#pragma unroll
                for (int r = 0; r < 4; ++r) {
                    int row = wp * 16 + lk * 4 + r;
                    ML[row * 2 + 0] = mrow[r];
                    ML[row * 2 + 1] = o9[r];
                }
            }
        }
        __syncthreads();
        if (s == 0) {
            float e0[4], e1[4], invl[4];
#pragma unroll
            for (int r = 0; r < 4; ++r) {
                int row = wp * 16 + lk * 4 + r;
                float m1 = ML[row * 2 + 0];
                float l1 = ML[row * 2 + 1];
                float l0 = __shfl(o9[r], lane & 48);
                float M = fmaxf(mrow[r], m1);
                e0[r] = fexp2(mrow[r] - M);
                e1[r] = fexp2(m1 - M);
                invl[r] = 1.f / (l0 * e0[r] + l1 * e1[r]);
            }
#pragma unroll
            for (int d = 0; d < 8; ++d)
#pragma unroll
                for (int r = 0; r < 4; ++r) {
                    int row = wp * 16 + lk * 4 + r;
                    float val = (o[d][r] * e0[r] +
                                 Ob[row * 128 + d * 16 + lm] * e1[r]) * invl[r];
                    Ao[((long)q0 + row) * 2048 + h * 128 + d * 16 + lm] = f2bf(val);
                }
        }
        __syncthreads();
    }
}

// ---------------- host launch ----------------
extern "C" void kernel_launch(void* const* d_in, const int* in_sizes, int n_in,
                              void* d_out, int out_size, void* d_ws, size_t ws_size,
                              hipStream_t stream) {
    (void)in_sizes; (void)n_in; (void)out_size; (void)ws_size;
    const float* hidden  = (const float*)d_in[0];
    const float* q_a_w   = (const float*)d_in[1];
    const float* q_a_ln  = (const float*)d_in[2];
    const float* q_b_w   = (const float*)d_in[3];
    const float* kv_a_w  = (const float*)d_in[4];
    const float* kv_a_ln = (const float*)d_in[5];
    const float* kv_b_w  = (const float*)d_in[6];
    const float* o_w     = (const float*)d_in[7];
    const float* cosT    = (const float*)d_in[8];
    const float* sinT    = (const float*)d_in[9];
    const int*   pos     = (const int*)d_in[11];

    char* ws = (char*)d_ws;
    // persistent zone
    u16* o_w_bf   = (u16*)(ws + 0);          // 2048x2048
    u16* qb_w_bf  = (u16*)(ws + 8388608);    // 3072x1536
    u16* kvb_w_bf = (u16*)(ws + 17825792);   // 4096x512
    u16* qn_bf    = (u16*)(ws + 22020096);   // 2048x1536
    u16* kvn_bf   = (u16*)(ws + 28311552);   // 2048x512
    u16* Qb       = (u16*)(ws + 30408704);   // 16x2048x192
    u16* Kb       = (u16*)(ws + 42991616);   // 16x2048x192
    u16* Vt       = (u16*)(ws + 55574528);   // 16x128x2048
    u16* aout_bf  = (u16*)(ws + 63963136);   // 2048x2048, ends 72351744
    // transient zone
    u16*   hid_bf    = (u16*)(ws + 72351744);   // 2048x2048 bf16
    u16*   qkva_w_bf = (u16*)(ws + 80740352);   // 2176x2048 bf16
    float* qkva_f    = (float*)(ws + 89653248); // 2048x2176 f32, ends 107479040

    // fused converts (6 segments, one launch)
    conv_all<<<19200, 256, 0, stream>>>(
        hidden, hid_bf,                 1048576L,
        q_a_w,  qkva_w_bf,              1835008L,
        q_b_w,  qb_w_bf,                3014656L,
        kv_b_w, kvb_w_bf,               3538944L,
        o_w,    o_w_bf,                 4587520L,
        kv_a_w, qkva_w_bf + 1536L*2048, 4915200L,
        576, 512);

    // fused down-projection: [2048,2048] x [2176,2048]^T -> [2048,2176] f32 (544 blocks)
    gemm64_db<float><<<dim3(17, 32), 256, 0, stream>>>(hid_bf, qkva_w_bf, qkva_f, 2048, 2176, 2048);

    // fused norms + k_pe rope (one launch)
    norm_rope<<<4352, 256, 0, stream>>>(qkva_f, q_a_ln, kv_a_ln, qn_bf, kvn_bf, pos, cosT, sinT, Kb);

    // fused up-projections: q_b (-> Qb w/ RoPE) + kv_b (-> Kb nope + Vt) in one launch
    gemm_qkv<<<1792, 256, 0, stream>>>(qn_bf, qb_w_bf, kvn_bf, kvb_w_bf, Qb, Kb, Vt, pos, cosT, sinT);

    // attention (256 blocks x 512 threads)
    attn_fwd<<<256, 512, 0, stream>>>(Qb, Kb, Vt, aout_bf);

    // output projection -> d_out (f32), 512 blocks
    gemm64_db<float><<<dim3(16, 32), 256, 0, stream>>>(aout_bf, o_w_bf, (float*)d_out, 2048, 2048, 2048);
}